// Round 1
// baseline (41606.256 us; speedup 1.0000x reference)
//
#include <hip/hip_runtime.h>

#define BB 64
#define TXX 512
#define DD 64
#define HH 1024
#define UU 512
#define TYY 16
#define G4 4096

using u16 = unsigned short;

__device__ __forceinline__ float bf2f(u16 v){ return __uint_as_float(((unsigned)v)<<16); }
__device__ __forceinline__ u16 f2bf(float f){
  unsigned u = __float_as_uint(f);
  u += 0x7FFF + ((u>>16)&1);
  return (u16)(u>>16);
}
__device__ __forceinline__ float sigm(float x){
  x = fminf(fmaxf(x,-30.f),30.f);
  return 1.f/(1.f+__expf(-x));
}
__device__ __forceinline__ float tanhfast(float x){
  x = fminf(fmaxf(x,-15.f),15.f);
  float e = __expf(2.f*x);
  return (e-1.f)/(e+1.f);
}

// ---------------- encoder step: z = x_t@Wk + h@Rk + b ; gates ; h,c update ----
// grid 256 blocks (4 hidden units each), 256 threads.
__global__ __launch_bounds__(256) void enc_step(
    const float* __restrict__ x, const float* __restrict__ Wk,
    const float* __restrict__ Rk, const float* __restrict__ bias,
    const float* __restrict__ hin, float* __restrict__ hout,
    float* __restrict__ cT, u16* __restrict__ yenc, int t)
{
  __shared__ float s[64*65];
  __shared__ float zs[64*17];
  const int tid = threadIdx.x;
  const int j0 = blockIdx.x*4;
  const int r  = tid & 63;
  const int cg = tid >> 6;     // gate index 0..3
  float a0=0.f,a1=0.f,a2=0.f,a3=0.f;

  // x contribution (K=64)
  #pragma unroll
  for (int it=0; it<16; ++it){
    int e = it*256 + tid;
    int row = e >> 6, d = e & 63;
    s[d*65 + row] = x[(size_t)row*(TXX*DD) + (size_t)t*DD + d];
  }
  __syncthreads();
  #pragma unroll 8
  for (int d=0; d<64; ++d){
    float hv = s[d*65 + r];
    float4 w4 = *reinterpret_cast<const float4*>(Wk + (size_t)d*G4 + cg*HH + j0);
    a0 = fmaf(hv,w4.x,a0); a1 = fmaf(hv,w4.y,a1);
    a2 = fmaf(hv,w4.z,a2); a3 = fmaf(hv,w4.w,a3);
  }
  // h contribution (K=1024), staged in 64-wide chunks
  for (int k0=0; k0<HH; k0+=64){
    __syncthreads();
    #pragma unroll
    for (int it=0; it<16; ++it){
      int e = it*256 + tid;
      int row = e >> 6, kk = e & 63;
      s[kk*65 + row] = hin[(size_t)row*HH + k0 + kk];
    }
    __syncthreads();
    #pragma unroll 8
    for (int kk=0; kk<64; ++kk){
      float hv = s[kk*65 + r];
      float4 w4 = *reinterpret_cast<const float4*>(Rk + (size_t)(k0+kk)*G4 + cg*HH + j0);
      a0 = fmaf(hv,w4.x,a0); a1 = fmaf(hv,w4.y,a1);
      a2 = fmaf(hv,w4.z,a2); a3 = fmaf(hv,w4.w,a3);
    }
  }
  // bias + exchange through LDS
  {
    const float* bp = bias + cg*HH + j0;
    zs[r*17 + cg*4 + 0] = a0 + bp[0];
    zs[r*17 + cg*4 + 1] = a1 + bp[1];
    zs[r*17 + cg*4 + 2] = a2 + bp[2];
    zs[r*17 + cg*4 + 3] = a3 + bp[3];
  }
  __syncthreads();
  // gates: thread -> (r, local hidden j=cg)
  {
    int j = cg;
    float zi = zs[r*17 + 0  + j];
    float zf = zs[r*17 + 4  + j];
    float zg = zs[r*17 + 8  + j];
    float zo = zs[r*17 + 12 + j];
    float cold = cT[(size_t)(j0+j)*BB + r];
    float cnew = sigm(zf)*cold + sigm(zi)*tanhfast(zg);
    float hnew = sigm(zo)*tanhfast(cnew);
    cT[(size_t)(j0+j)*BB + r] = cnew;
    s[j*64 + r] = hnew;
  }
  __syncthreads();
  if (tid < 64){
    int rr = tid;
    float h0v = s[0*64+rr], h1v = s[1*64+rr], h2v = s[2*64+rr], h3v = s[3*64+rr];
    *reinterpret_cast<float4*>(hout + (size_t)rr*HH + j0) = make_float4(h0v,h1v,h2v,h3v);
    ushort4 yv;
    yv.x = f2bf(h0v); yv.y = f2bf(h1v); yv.z = f2bf(h2v); yv.w = f2bf(h3v);
    *reinterpret_cast<ushort4*>(yenc + ((size_t)rr*TXX + t)*HH + j0) = yv;
  }
}

// ---------------- decoder LSTM step ------------------------------------------
__global__ __launch_bounds__(256) void dec_step(
    const float* __restrict__ ctx, const float* __restrict__ Wk,
    const float* __restrict__ Rk, const float* __restrict__ bias,
    const float* __restrict__ yprev,
    const float* __restrict__ hin, float* __restrict__ hout,
    float* __restrict__ cT)
{
  __shared__ float s[64*65];
  __shared__ float zs[64*17];
  __shared__ float yp[64];
  const int tid = threadIdx.x;
  const int j0 = blockIdx.x*4;
  const int r  = tid & 63;
  const int cg = tid >> 6;
  if (tid < 64) yp[tid] = yprev[tid];
  float a0=0.f,a1=0.f,a2=0.f,a3=0.f;

  // ctx contribution: dec_k rows 1..1024
  for (int k0=0; k0<HH; k0+=64){
    __syncthreads();
    #pragma unroll
    for (int it=0; it<16; ++it){
      int e = it*256 + tid;
      int row = e >> 6, kk = e & 63;
      s[kk*65 + row] = ctx[(size_t)row*HH + k0 + kk];
    }
    __syncthreads();
    #pragma unroll 8
    for (int kk=0; kk<64; ++kk){
      float hv = s[kk*65 + r];
      float4 w4 = *reinterpret_cast<const float4*>(Wk + (size_t)(1+k0+kk)*G4 + cg*HH + j0);
      a0 = fmaf(hv,w4.x,a0); a1 = fmaf(hv,w4.y,a1);
      a2 = fmaf(hv,w4.z,a2); a3 = fmaf(hv,w4.w,a3);
    }
  }
  // h contribution
  for (int k0=0; k0<HH; k0+=64){
    __syncthreads();
    #pragma unroll
    for (int it=0; it<16; ++it){
      int e = it*256 + tid;
      int row = e >> 6, kk = e & 63;
      s[kk*65 + row] = hin[(size_t)row*HH + k0 + kk];
    }
    __syncthreads();
    #pragma unroll 8
    for (int kk=0; kk<64; ++kk){
      float hv = s[kk*65 + r];
      float4 w4 = *reinterpret_cast<const float4*>(Rk + (size_t)(k0+kk)*G4 + cg*HH + j0);
      a0 = fmaf(hv,w4.x,a0); a1 = fmaf(hv,w4.y,a1);
      a2 = fmaf(hv,w4.z,a2); a3 = fmaf(hv,w4.w,a3);
    }
  }
  // y_prev term (dec_k row 0) + bias, exchange
  {
    float ypv = yp[r];
    const float* w0 = Wk + cg*HH + j0;
    const float* bp = bias + cg*HH + j0;
    zs[r*17 + cg*4 + 0] = fmaf(ypv,w0[0],a0) + bp[0];
    zs[r*17 + cg*4 + 1] = fmaf(ypv,w0[1],a1) + bp[1];
    zs[r*17 + cg*4 + 2] = fmaf(ypv,w0[2],a2) + bp[2];
    zs[r*17 + cg*4 + 3] = fmaf(ypv,w0[3],a3) + bp[3];
  }
  __syncthreads();
  {
    int j = cg;
    float zi = zs[r*17 + 0  + j];
    float zf = zs[r*17 + 4  + j];
    float zg = zs[r*17 + 8  + j];
    float zo = zs[r*17 + 12 + j];
    float cold = cT[(size_t)(j0+j)*BB + r];
    float cnew = sigm(zf)*cold + sigm(zi)*tanhfast(zg);
    float hnew = sigm(zo)*tanhfast(cnew);
    cT[(size_t)(j0+j)*BB + r] = cnew;
    s[j*64 + r] = hnew;
  }
  __syncthreads();
  if (tid < 64){
    int rr = tid;
    *reinterpret_cast<float4*>(hout + (size_t)rr*HH + j0) =
        make_float4(s[0*64+rr], s[1*64+rr], s[2*64+rr], s[3*64+rr]);
  }
}

// ---------------- Eenc = y_enc @ att_w1[:H] + b1  (bf16 out) ------------------
// grid (512, 8), block 256, 64x64 tile, 4x4 micro
__global__ __launch_bounds__(256) void eenc_gemm(
   const u16* __restrict__ yenc, const float* __restrict__ w1,
   const float* __restrict__ b1, u16* __restrict__ eenc)
{
  __shared__ float As[32*68];
  __shared__ float Bs[32*68];
  const int tid = threadIdx.x;
  const int m0 = blockIdx.x*64, n0 = blockIdx.y*64;
  const int tx = tid & 15, ty = tid >> 4;
  float acc[4][4] = {};
  for (int k0=0; k0<HH; k0+=32){
    #pragma unroll
    for (int it=0; it<8; ++it){
      int e = it*256 + tid;
      int row = e >> 5, kk = e & 31;
      As[kk*68 + row] = bf2f(yenc[(size_t)(m0+row)*HH + k0 + kk]);
    }
    #pragma unroll
    for (int it=0; it<8; ++it){
      int e = it*256 + tid;
      int kk = e >> 6, col = e & 63;
      Bs[kk*68 + col] = w1[(size_t)(k0+kk)*UU + n0 + col];
    }
    __syncthreads();
    #pragma unroll
    for (int kk=0; kk<32; ++kk){
      float4 av = *reinterpret_cast<const float4*>(&As[kk*68 + ty*4]);
      float4 bv = *reinterpret_cast<const float4*>(&Bs[kk*68 + tx*4]);
      acc[0][0]=fmaf(av.x,bv.x,acc[0][0]); acc[0][1]=fmaf(av.x,bv.y,acc[0][1]);
      acc[0][2]=fmaf(av.x,bv.z,acc[0][2]); acc[0][3]=fmaf(av.x,bv.w,acc[0][3]);
      acc[1][0]=fmaf(av.y,bv.x,acc[1][0]); acc[1][1]=fmaf(av.y,bv.y,acc[1][1]);
      acc[1][2]=fmaf(av.y,bv.z,acc[1][2]); acc[1][3]=fmaf(av.y,bv.w,acc[1][3]);
      acc[2][0]=fmaf(av.z,bv.x,acc[2][0]); acc[2][1]=fmaf(av.z,bv.y,acc[2][1]);
      acc[2][2]=fmaf(av.z,bv.z,acc[2][2]); acc[2][3]=fmaf(av.z,bv.w,acc[2][3]);
      acc[3][0]=fmaf(av.w,bv.x,acc[3][0]); acc[3][1]=fmaf(av.w,bv.y,acc[3][1]);
      acc[3][2]=fmaf(av.w,bv.z,acc[3][2]); acc[3][3]=fmaf(av.w,bv.w,acc[3][3]);
    }
    __syncthreads();
  }
  float bb0 = b1[n0+tx*4+0], bb1 = b1[n0+tx*4+1], bb2 = b1[n0+tx*4+2], bb3 = b1[n0+tx*4+3];
  #pragma unroll
  for (int i=0;i<4;++i){
    ushort4 ov;
    ov.x = f2bf(acc[i][0]+bb0); ov.y = f2bf(acc[i][1]+bb1);
    ov.z = f2bf(acc[i][2]+bb2); ov.w = f2bf(acc[i][3]+bb3);
    *reinterpret_cast<ushort4*>(eenc + (size_t)(m0+ty*4+i)*UU + n0 + tx*4) = ov;
  }
}

// ---------------- hW = h @ att_w1[H:]  (no bias) ------------------------------
// grid 32, block 256: block owns 16 u columns
__global__ __launch_bounds__(256) void hw_gemm(
  const float* __restrict__ hin, const float* __restrict__ w1,
  float* __restrict__ hW)
{
  __shared__ float s[64*65];
  const int tid = threadIdx.x;
  const int u0 = blockIdx.x*16;
  const int r = tid & 63, cg = tid >> 6;
  float a0=0.f,a1=0.f,a2=0.f,a3=0.f;
  for (int k0=0; k0<HH; k0+=64){
    __syncthreads();
    #pragma unroll
    for (int it=0; it<16; ++it){
      int e = it*256 + tid;
      int row = e >> 6, kk = e & 63;
      s[kk*65 + row] = hin[(size_t)row*HH + k0 + kk];
    }
    __syncthreads();
    #pragma unroll 8
    for (int kk=0; kk<64; ++kk){
      float hv = s[kk*65 + r];
      float4 w4 = *reinterpret_cast<const float4*>(w1 + (size_t)(HH + k0+kk)*UU + u0 + cg*4);
      a0 = fmaf(hv,w4.x,a0); a1 = fmaf(hv,w4.y,a1);
      a2 = fmaf(hv,w4.z,a2); a3 = fmaf(hv,w4.w,a3);
    }
  }
  *reinterpret_cast<float4*>(hW + (size_t)r*UU + u0 + cg*4) = make_float4(a0,a1,a2,a3);
}

// ---------------- scores: e2 = relu( tanh(Eenc + hW) . w2 + b2 ) --------------
// grid 8192, block 256 (4 waves, one (b,t) pair each)
__global__ __launch_bounds__(256) void att_scores(
  const u16* __restrict__ eenc, const float* __restrict__ hW,
  const float* __restrict__ w2, const float* __restrict__ b2,
  float* __restrict__ e2)
{
  const int tid = threadIdx.x;
  const int lane = tid & 63;
  const int p = blockIdx.x*4 + (tid>>6);
  const int b = p >> 9;
  const int u0 = lane*8;
  uint4 ev = *reinterpret_cast<const uint4*>(eenc + (size_t)p*UU + u0);
  float4 hw0 = *reinterpret_cast<const float4*>(hW + (size_t)b*UU + u0);
  float4 hw1 = *reinterpret_cast<const float4*>(hW + (size_t)b*UU + u0 + 4);
  float4 w20 = *reinterpret_cast<const float4*>(w2 + u0);
  float4 w21 = *reinterpret_cast<const float4*>(w2 + u0 + 4);
  float sum;
  sum  = tanhfast(bf2f((u16)(ev.x & 0xffff)) + hw0.x) * w20.x;
  sum += tanhfast(bf2f((u16)(ev.x >> 16   )) + hw0.y) * w20.y;
  sum += tanhfast(bf2f((u16)(ev.y & 0xffff)) + hw0.z) * w20.z;
  sum += tanhfast(bf2f((u16)(ev.y >> 16   )) + hw0.w) * w20.w;
  sum += tanhfast(bf2f((u16)(ev.z & 0xffff)) + hw1.x) * w21.x;
  sum += tanhfast(bf2f((u16)(ev.z >> 16   )) + hw1.y) * w21.y;
  sum += tanhfast(bf2f((u16)(ev.w & 0xffff)) + hw1.z) * w21.z;
  sum += tanhfast(bf2f((u16)(ev.w >> 16   )) + hw1.w) * w21.w;
  #pragma unroll
  for (int off=32; off; off>>=1) sum += __shfl_down(sum, off);
  if (lane==0) e2[p] = fmaxf(sum + b2[0], 0.f);
}

// ---------------- softmax over t ---------------------------------------------
__global__ __launch_bounds__(256) void att_softmax(
  const float* __restrict__ e2, float* __restrict__ wat,
  float* __restrict__ outw, int writeOut)
{
  __shared__ float red[256];
  const int b = blockIdx.x, tid = threadIdx.x;
  float v1 = e2[b*TXX + tid], v2 = e2[b*TXX + 256 + tid];
  red[tid] = fmaxf(v1,v2); __syncthreads();
  for (int sft=128; sft; sft>>=1){ if (tid<sft) red[tid] = fmaxf(red[tid], red[tid+sft]); __syncthreads(); }
  float m = red[0]; __syncthreads();
  float x1 = __expf(v1-m), x2 = __expf(v2-m);
  red[tid] = x1+x2; __syncthreads();
  for (int sft=128; sft; sft>>=1){ if (tid<sft) red[tid] += red[tid+sft]; __syncthreads(); }
  float inv = 1.f/red[0];
  float w1v = x1*inv, w2v = x2*inv;
  wat[b*TXX+tid] = w1v; wat[b*TXX+256+tid] = w2v;
  if (writeOut){
    outw[64 + b*TXX + tid] = w1v;
    outw[64 + b*TXX + 256 + tid] = w2v;
  }
}

// ---------------- ctx: two-stage weighted sum over t --------------------------
__global__ __launch_bounds__(256) void ctx_part(
  const float* __restrict__ wat, const u16* __restrict__ yenc,
  float* __restrict__ part)
{
  __shared__ float ws[64];
  const int b = blockIdx.x, tc = blockIdx.y;
  const int tid = threadIdx.x;
  if (tid < 64) ws[tid] = wat[b*TXX + tc*64 + tid];
  __syncthreads();
  const int h0 = tid*4;
  float a0=0.f,a1=0.f,a2=0.f,a3=0.f;
  #pragma unroll 8
  for (int tt=0; tt<64; ++tt){
    float w = ws[tt];
    ushort4 yv = *reinterpret_cast<const ushort4*>(yenc + ((size_t)(b*TXX + tc*64 + tt))*HH + h0);
    a0 = fmaf(w, bf2f(yv.x), a0); a1 = fmaf(w, bf2f(yv.y), a1);
    a2 = fmaf(w, bf2f(yv.z), a2); a3 = fmaf(w, bf2f(yv.w), a3);
  }
  *reinterpret_cast<float4*>(part + ((size_t)(b*8+tc))*HH + h0) = make_float4(a0,a1,a2,a3);
}

__global__ __launch_bounds__(256) void ctx_reduce(
  const float* __restrict__ part, float* __restrict__ ctx)
{
  const int i = blockIdx.x*256 + threadIdx.x; // i = b*1024 + h
  const int b = i >> 10, hh = i & 1023;
  float sum = 0.f;
  #pragma unroll
  for (int tc=0; tc<8; ++tc) sum += part[((size_t)(b*8+tc))*HH + hh];
  ctx[i] = sum;
}

// ---------------- final y = h @ fin_w + fin_b --------------------------------
__global__ __launch_bounds__(256) void final_y(
  const float* __restrict__ h, const float* __restrict__ fw,
  const float* __restrict__ fb, float* __restrict__ yprev,
  float* __restrict__ outy, int writeOut)
{
  __shared__ float red[256];
  const int b = blockIdx.x, tid = threadIdx.x;
  float4 hv = *reinterpret_cast<const float4*>(h + (size_t)b*HH + tid*4);
  float4 wv = *reinterpret_cast<const float4*>(fw + tid*4);
  red[tid] = hv.x*wv.x + hv.y*wv.y + hv.z*wv.z + hv.w*wv.w;
  __syncthreads();
  for (int sft=128; sft; sft>>=1){ if (tid<sft) red[tid] += red[tid+sft]; __syncthreads(); }
  if (tid==0){
    float y = red[0] + fb[0];
    yprev[b] = y;
    if (writeOut) outy[b] = y;
  }
}

__global__ void init_yprev(const float* __restrict__ x, float* __restrict__ yprev){
  int b = threadIdx.x;
  if (b < BB) yprev[b] = x[(size_t)b*TXX*DD + (size_t)(TXX-1)*DD + (DD-1)];
}

extern "C" void kernel_launch(void* const* d_in, const int* in_sizes, int n_in,
                              void* d_out, int out_size, void* d_ws, size_t ws_size,
                              hipStream_t stream)
{
  (void)in_sizes; (void)n_in; (void)out_size; (void)ws_size;
  const float* x      = (const float*)d_in[0];
  const float* enc_k  = (const float*)d_in[1];
  const float* enc_rk = (const float*)d_in[2];
  const float* enc_b  = (const float*)d_in[3];
  const float* dec_k  = (const float*)d_in[4];
  const float* dec_rk = (const float*)d_in[5];
  const float* dec_b  = (const float*)d_in[6];
  const float* att_w1 = (const float*)d_in[7];
  const float* att_b1 = (const float*)d_in[8];
  const float* att_w2 = (const float*)d_in[9];
  const float* att_b2 = (const float*)d_in[10];
  const float* fin_w  = (const float*)d_in[11];
  const float* fin_b  = (const float*)d_in[12];
  float* out = (float*)d_out;

  char* w = (char*)d_ws;
  u16*   yenc = (u16*)(w);                       // 64 MB
  u16*   eenc = (u16*)(w + 67108864);            // 32 MB
  float* hA   = (float*)(w + 100663296);         // 256 KB
  float* hB   = (float*)(w + 100925440);         // 256 KB
  float* cT   = (float*)(w + 101187584);         // 256 KB
  float* hW   = (float*)(w + 101449728);         // 128 KB
  float* e2   = (float*)(w + 101580800);         // 128 KB
  float* wat  = (float*)(w + 101711872);         // 128 KB
  float* ctx  = (float*)(w + 101843968);         // 256 KB
  float* part = (float*)(w + 102106112);         // 2 MB
  float* yprev= (float*)(w + 104203264);         // 256 B

  hipMemsetAsync(hA, 0, 262144*3, stream);       // hA, hB, cT
  init_yprev<<<1, 64, 0, stream>>>(x, yprev);

  // -------- encoder: 512 sequential steps, ping-pong h ----------------------
  for (int t=0; t<TXX; ++t){
    const float* hi = (t&1)? hB : hA;
    float*       ho = (t&1)? hA : hB;
    enc_step<<<256, 256, 0, stream>>>(x, enc_k, enc_rk, enc_b, hi, ho, cT, yenc, t);
  }
  // final encoder h is in hA (t=511 wrote hA)

  // -------- hoisted attention GEMM: Eenc = y_enc @ w1[:H] + b1 --------------
  eenc_gemm<<<dim3(512,8), 256, 0, stream>>>(yenc, att_w1, att_b1, eenc);

  // -------- decoder: 16 steps ----------------------------------------------
  for (int s=0; s<TYY; ++s){
    const float* hi = (s&1)? hB : hA;
    float*       ho = (s&1)? hA : hB;
    int last = (s == TYY-1);
    hw_gemm   <<<32, 256, 0, stream>>>(hi, att_w1, hW);
    att_scores<<<8192, 256, 0, stream>>>(eenc, hW, att_w2, att_b2, e2);
    att_softmax<<<64, 256, 0, stream>>>(e2, wat, out, last);
    ctx_part  <<<dim3(64,8), 256, 0, stream>>>(wat, yenc, part);
    ctx_reduce<<<256, 256, 0, stream>>>(part, ctx);
    dec_step  <<<256, 256, 0, stream>>>(ctx, dec_k, dec_rk, dec_b, yprev, hi, ho, cT);
    final_y   <<<64, 256, 0, stream>>>(ho, fin_w, fin_b, yprev, out, last);
  }
}

// Round 2
// 16168.770 us; speedup vs baseline: 2.5732x; 2.5732x over previous
//
#include <hip/hip_runtime.h>

#define BB 64
#define TXX 512
#define DD 64
#define HH 1024
#define UU 512
#define TYY 16
#define G4 4096

using u16 = unsigned short;
typedef __attribute__((ext_vector_type(8))) short short8;
typedef __attribute__((ext_vector_type(4))) float f32x4;

__device__ __forceinline__ float bf2f(u16 v){ return __uint_as_float(((unsigned)v)<<16); }
__device__ __forceinline__ u16 f2bf(float f){
  unsigned u = __float_as_uint(f);
  u += 0x7FFF + ((u>>16)&1);
  return (u16)(u>>16);
}
__device__ __forceinline__ float sigm(float x){
  x = fminf(fmaxf(x,-30.f),30.f);
  return 1.f/(1.f+__expf(-x));
}
__device__ __forceinline__ float tanhfast(float x){
  x = fminf(fmaxf(x,-15.f),15.f);
  float e = __expf(2.f*x);
  return (e-1.f)/(e+1.f);
}

// ---------------- two-level monotonic grid barrier (256 blocks) --------------
__device__ __forceinline__ void gbar(unsigned* bar, int bid, unsigned bk){
  __syncthreads();
  if (threadIdx.x == 0){
    unsigned* cnt  = bar + (bid>>4)*32;   // 16 groups, 128B apart
    unsigned* root = bar + 512;
    unsigned* gen  = bar + 544;
    __threadfence();
    if (__hip_atomic_fetch_add(cnt, 1u, __ATOMIC_ACQ_REL, __HIP_MEMORY_SCOPE_AGENT) == bk*16u + 15u){
      if (__hip_atomic_fetch_add(root, 1u, __ATOMIC_ACQ_REL, __HIP_MEMORY_SCOPE_AGENT) == bk*16u + 15u){
        __hip_atomic_fetch_add(gen, 1u, __ATOMIC_ACQ_REL, __HIP_MEMORY_SCOPE_AGENT);
      } else {
        while (__hip_atomic_load(gen, __ATOMIC_ACQUIRE, __HIP_MEMORY_SCOPE_AGENT) <= bk)
          __builtin_amdgcn_s_sleep(2);
      }
    } else {
      while (__hip_atomic_load(gen, __ATOMIC_ACQUIRE, __HIP_MEMORY_SCOPE_AGENT) <= bk)
        __builtin_amdgcn_s_sleep(2);
    }
  }
  __syncthreads();
}

// ---------------- persistent encoder: weights in registers ------------------
// 256 blocks x 256 thr. Block owns h-cols j0..j0+3 (16 z-cols across 4 gates).
// LDS: h stage [64][1024] bf16 swizzled (131072) + zex 64x17 f32 (4352) + c 64x4 f32 (1024)
__global__ __launch_bounds__(256, 1) void enc_persist(
    const float* __restrict__ x, const float* __restrict__ enc_k_,
    const float* __restrict__ enc_rk_, const float* __restrict__ enc_b_,
    u16* __restrict__ hbuf, u16* __restrict__ yenc,
    float* __restrict__ cdec, unsigned* __restrict__ bar)
{
  extern __shared__ char smem[];
  float* zex = (float*)(smem + 131072);
  float* cst = (float*)(smem + 131072 + 4352);
  const int tid = threadIdx.x, bid = blockIdx.x;
  const int l = tid & 63, w = tid >> 6;
  const int c = l & 15, koct = l >> 4;
  const int j0 = bid*4;
  const int gcol = (c>>2)*1024 + j0 + (c&3);

  // gather recurrent-weight B fragments into registers (one time)
  short8 bR[32];
  #pragma unroll
  for (int kk=0; kk<32; ++kk){
    short8 f;
    #pragma unroll
    for (int i=0; i<8; ++i)
      f[i] = (short)f2bf(enc_rk_[(size_t)(kk*32 + koct*8 + i)*G4 + gcol]);
    bR[kk] = f;
  }
  short8 bK[2];
  #pragma unroll
  for (int kk=0; kk<2; ++kk){
    short8 f;
    #pragma unroll
    for (int i=0; i<8; ++i)
      f[i] = (short)f2bf(enc_k_[(size_t)(kk*32 + koct*8 + i)*G4 + gcol]);
    bK[kk] = f;
  }
  const float sbias = enc_b_[gcol];
  if (tid < 64){
    cst[tid*4+0]=0.f; cst[tid*4+1]=0.f; cst[tid*4+2]=0.f; cst[tid*4+3]=0.f;
  }
  const int arow  = w*16 + c;          // batch row for A fragments
  const int rbase = arow*2048;
  const int xorv  = (arow&7)<<4;
  const int bb = tid & 63, jj = tid >> 6;  // gate-phase mapping

  for (int t=0; t<TXX; ++t){
    if (t) gbar(bar, bid, (unsigned)(t-1));
    const u16* hcur = hbuf + (size_t)(t&1)*65536;
    u16* hnxt = hbuf + (size_t)((t+1)&1)*65536;

    // x_t fragments straight from global fp32
    short8 ax[2];
    #pragma unroll
    for (int kk=0; kk<2; ++kk){
      const float* xp = x + (size_t)arow*(TXX*DD) + (size_t)t*DD + kk*32 + koct*8;
      short8 f;
      #pragma unroll
      for (int i=0; i<8; ++i) f[i] = (short)f2bf(xp[i]);
      ax[kk] = f;
    }
    // stage h into swizzled LDS (reg-staged, coalesced)
    const short8* src = (const short8*)hcur;
    #pragma unroll 4
    for (int p=0; p<32; ++p){
      int e = p*256 + tid;
      int byte = e*16;
      int row = byte>>11;
      int waddr = byte ^ ((row&7)<<4);
      *(short8*)(smem + waddr) = src[e];
    }
    __syncthreads();

    f32x4 acc = {0.f,0.f,0.f,0.f};
    acc = __builtin_amdgcn_mfma_f32_16x16x32_bf16(ax[0], bK[0], acc, 0,0,0);
    acc = __builtin_amdgcn_mfma_f32_16x16x32_bf16(ax[1], bK[1], acc, 0,0,0);
    #pragma unroll
    for (int kk=0; kk<32; ++kk){
      int addr = rbase + ((kk*64 + koct*16) ^ xorv);
      short8 af = *(const short8*)(smem + addr);
      acc = __builtin_amdgcn_mfma_f32_16x16x32_bf16(af, bR[kk], acc, 0,0,0);
    }
    #pragma unroll
    for (int j=0; j<4; ++j)
      zex[(w*16 + koct*4 + j)*17 + c] = acc[j] + sbias;
    __syncthreads();
    // gates: thread -> (batch bb, local col jj)
    {
      float zi = zex[bb*17 + jj];
      float zf = zex[bb*17 + 4 + jj];
      float zg = zex[bb*17 + 8 + jj];
      float zo = zex[bb*17 + 12 + jj];
      float cold = cst[bb*4 + jj];
      float cnew = sigm(zf)*cold + sigm(zi)*tanhfast(zg);
      float hnew = sigm(zo)*tanhfast(cnew);
      cst[bb*4 + jj] = cnew;
      u16 hb = f2bf(hnew);
      hnxt[bb*HH + j0 + jj] = hb;
      yenc[((size_t)bb*TXX + t)*HH + j0 + jj] = hb;
      if (t == TXX-1) cdec[(j0+jj)*BB + bb] = cnew;
    }
  }
}

// ---------------- Eenc = y_enc @ w1b[:H] + b1 (bf16 out, MFMA) ---------------
// grid (256,8), 256 thr, tile 128M x 64N
__global__ __launch_bounds__(256) void eenc_mfma(
    const u16* __restrict__ yenc, const u16* __restrict__ w1b,
    const float* __restrict__ b1, u16* __restrict__ eenc)
{
  __shared__ u16 As[128*40];   // stride 40 u16 (80 B)
  __shared__ u16 Bs[64*40];
  const int tid = threadIdx.x;
  const int l = tid&63, wm = tid>>6;
  const int c = l&15, koct = l>>4;
  const int m0 = blockIdx.x*128, n0 = blockIdx.y*64;
  f32x4 acc[2][4];
  #pragma unroll
  for (int a=0;a<2;++a)
    #pragma unroll
    for (int b=0;b<4;++b) acc[a][b] = (f32x4){0.f,0.f,0.f,0.f};

  for (int k0=0; k0<HH; k0+=32){
    #pragma unroll
    for (int p=0; p<2; ++p){
      int e = p*256 + tid;       // 512 chunks of 16B
      int row = e>>2, k16 = e&3;
      *(short8*)((char*)As + row*80 + k16*16) =
        *(const short8*)(yenc + (size_t)(m0+row)*HH + k0 + k16*8);
    }
    #pragma unroll
    for (int p=0; p<8; ++p){
      int e = p*256 + tid;       // 2048 elems, transpose
      int kk = e>>6, col = e&63;
      Bs[col*40 + kk] = w1b[(size_t)(k0+kk)*UU + n0 + col];
    }
    __syncthreads();
    short8 af[2];
    #pragma unroll
    for (int mt=0; mt<2; ++mt)
      af[mt] = *(const short8*)((const char*)As + (wm*32+mt*16+c)*80 + koct*16);
    #pragma unroll
    for (int nt=0; nt<4; ++nt){
      short8 bf = *(const short8*)((const char*)Bs + (nt*16+c)*80 + koct*16);
      acc[0][nt] = __builtin_amdgcn_mfma_f32_16x16x32_bf16(af[0], bf, acc[0][nt], 0,0,0);
      acc[1][nt] = __builtin_amdgcn_mfma_f32_16x16x32_bf16(af[1], bf, acc[1][nt], 0,0,0);
    }
    __syncthreads();
  }
  #pragma unroll
  for (int nt=0; nt<4; ++nt){
    float sb = b1[n0 + nt*16 + c];
    #pragma unroll
    for (int mt=0; mt<2; ++mt){
      #pragma unroll
      for (int j=0; j<4; ++j){
        int row = m0 + wm*32 + mt*16 + koct*4 + j;
        eenc[(size_t)row*UU + n0 + nt*16 + c] = f2bf(acc[mt][nt][j] + sb);
      }
    }
  }
}

// ---------------- hW = h @ w1b[H:] (MFMA) ------------------------------------
// grid 32, 256 thr, block owns 16 u-cols
__global__ __launch_bounds__(256) void hw_mfma(
    const u16* __restrict__ hdec, const u16* __restrict__ w1b,
    float* __restrict__ hW)
{
  extern __shared__ char smem[];
  u16* As = (u16*)smem;              // 64 x stride 520 u16 (1040 B) = 66560
  u16* Ws = (u16*)(smem + 66560);    // 512 x stride 19 u16 = 19456
  const int tid = threadIdx.x;
  const int l = tid&63, w = tid>>6;
  const int c = l&15, koct = l>>4;
  const int u0 = blockIdx.x*16;
  f32x4 acc = {0.f,0.f,0.f,0.f};
  for (int ch=0; ch<2; ++ch){
    #pragma unroll
    for (int p=0; p<16; ++p){
      int e = p*256 + tid;       // 4096 16B chunks
      int row = e>>6, k16 = e&63;
      *(short8*)((char*)As + row*1040 + k16*16) =
        *(const short8*)(hdec + (size_t)row*HH + ch*512 + k16*8);
    }
    #pragma unroll
    for (int p=0; p<32; ++p){
      int e = p*256 + tid;       // 8192 elems
      int kk = e>>4, cc = e&15;
      Ws[kk*19 + cc] = w1b[(size_t)(HH + ch*512 + kk)*UU + u0 + cc];
    }
    __syncthreads();
    #pragma unroll
    for (int s=0; s<16; ++s){
      short8 af = *(const short8*)((const char*)As + (w*16+c)*1040 + s*64 + koct*16);
      short8 bf;
      #pragma unroll
      for (int i=0; i<8; ++i) bf[i] = (short)Ws[(s*32 + koct*8 + i)*19 + c];
      acc = __builtin_amdgcn_mfma_f32_16x16x32_bf16(af, bf, acc, 0,0,0);
    }
    __syncthreads();
  }
  #pragma unroll
  for (int j=0; j<4; ++j)
    hW[(size_t)(w*16 + koct*4 + j)*UU + u0 + c] = acc[j];
}

// ---------------- scores: e2 = relu( tanh(Eenc + hW) . w2 + b2 ) --------------
__global__ __launch_bounds__(256) void att_scores(
  const u16* __restrict__ eenc, const float* __restrict__ hW,
  const float* __restrict__ w2, const float* __restrict__ b2,
  float* __restrict__ e2)
{
  const int tid = threadIdx.x;
  const int lane = tid & 63;
  const int p = blockIdx.x*4 + (tid>>6);
  const int b = p >> 9;
  const int u0 = lane*8;
  uint4 ev = *reinterpret_cast<const uint4*>(eenc + (size_t)p*UU + u0);
  float4 hw0 = *reinterpret_cast<const float4*>(hW + (size_t)b*UU + u0);
  float4 hw1 = *reinterpret_cast<const float4*>(hW + (size_t)b*UU + u0 + 4);
  float4 w20 = *reinterpret_cast<const float4*>(w2 + u0);
  float4 w21 = *reinterpret_cast<const float4*>(w2 + u0 + 4);
  float sum;
  sum  = tanhfast(bf2f((u16)(ev.x & 0xffff)) + hw0.x) * w20.x;
  sum += tanhfast(bf2f((u16)(ev.x >> 16   )) + hw0.y) * w20.y;
  sum += tanhfast(bf2f((u16)(ev.y & 0xffff)) + hw0.z) * w20.z;
  sum += tanhfast(bf2f((u16)(ev.y >> 16   )) + hw0.w) * w20.w;
  sum += tanhfast(bf2f((u16)(ev.z & 0xffff)) + hw1.x) * w21.x;
  sum += tanhfast(bf2f((u16)(ev.z >> 16   )) + hw1.y) * w21.y;
  sum += tanhfast(bf2f((u16)(ev.w & 0xffff)) + hw1.z) * w21.z;
  sum += tanhfast(bf2f((u16)(ev.w >> 16   )) + hw1.w) * w21.w;
  #pragma unroll
  for (int off=32; off; off>>=1) sum += __shfl_down(sum, off);
  if (lane==0) e2[p] = fmaxf(sum + b2[0], 0.f);
}

// ---------------- softmax over t (in-place on e2) ----------------------------
__global__ __launch_bounds__(256) void att_softmax(
  float* __restrict__ e2, float* __restrict__ outw, int writeOut)
{
  __shared__ float red[256];
  const int b = blockIdx.x, tid = threadIdx.x;
  float v1 = e2[b*TXX + tid], v2 = e2[b*TXX + 256 + tid];
  red[tid] = fmaxf(v1,v2); __syncthreads();
  for (int sft=128; sft; sft>>=1){ if (tid<sft) red[tid] = fmaxf(red[tid], red[tid+sft]); __syncthreads(); }
  float m = red[0]; __syncthreads();
  float x1 = __expf(v1-m), x2 = __expf(v2-m);
  red[tid] = x1+x2; __syncthreads();
  for (int sft=128; sft; sft>>=1){ if (tid<sft) red[tid] += red[tid+sft]; __syncthreads(); }
  float inv = 1.f/red[0];
  float w1v = x1*inv, w2v = x2*inv;
  e2[b*TXX+tid] = w1v; e2[b*TXX+256+tid] = w2v;
  if (writeOut){
    outw[64 + b*TXX + tid] = w1v;
    outw[64 + b*TXX + 256 + tid] = w2v;
  }
}

// ---------------- ctx = sum_t w[t]*y_enc[b,t,:] ------------------------------
__global__ __launch_bounds__(256) void ctx_sum(
  const float* __restrict__ wat, const u16* __restrict__ yenc,
  float* __restrict__ ctx)
{
  __shared__ float wl[512];
  const int b = blockIdx.x, tid = threadIdx.x;
  wl[tid] = wat[b*TXX + tid];
  wl[256+tid] = wat[b*TXX + 256 + tid];
  __syncthreads();
  const int h0 = tid*4;
  float a0=0.f,a1=0.f,a2=0.f,a3=0.f;
  #pragma unroll 8
  for (int t=0; t<512; ++t){
    float wv = wl[t];
    ushort4 yv = *(const ushort4*)(yenc + ((size_t)b*TXX + t)*HH + h0);
    a0 = fmaf(wv, bf2f(yv.x), a0); a1 = fmaf(wv, bf2f(yv.y), a1);
    a2 = fmaf(wv, bf2f(yv.z), a2); a3 = fmaf(wv, bf2f(yv.w), a3);
  }
  *(float4*)(ctx + (size_t)b*HH + h0) = make_float4(a0,a1,a2,a3);
}

// ---------------- assemble decoder A = [yprev | ctx | h | 0pad] bf16 ---------
__global__ __launch_bounds__(256) void assemble_A(
  const float* __restrict__ yprev, const float* __restrict__ ctx,
  const u16* __restrict__ hdec, u16* __restrict__ Adec)
{
  int e = blockIdx.x*256 + threadIdx.x;  // 520*256 = 133120 = 64*2080
  int b = e/2080, cc = e - b*2080;
  float v;
  if (cc == 0) v = yprev[b];
  else if (cc <= 1024) v = ctx[b*HH + cc-1];
  else if (cc <= 2048) v = bf2f(hdec[b*HH + cc-1025]);
  else v = 0.f;
  Adec[e] = f2bf(v);
}

// ---------------- decoder LSTM (MFMA), weights bf16-converted on the fly -----
// grid 256, 256 thr; block owns h-cols j0..j0+3 (16 z-cols)
__global__ __launch_bounds__(256) void dec_mfma(
    const u16* __restrict__ Adec, const float* __restrict__ dec_k_,
    const float* __restrict__ dec_rk_, const float* __restrict__ dec_b_,
    float* __restrict__ cdec, u16* __restrict__ hdec)
{
  extern __shared__ char smem[];
  u16* As = (u16*)smem;                    // 64 x 848 B = 54272
  u16* Ws = (u16*)(smem + 54272);          // 416 x stride 19 u16 = 15808
  float* zex = (float*)(smem + 54272 + 15808);  // 4352
  const int tid = threadIdx.x;
  const int l = tid&63, w = tid>>6;
  const int c = l&15, koct = l>>4;
  const int j0 = blockIdx.x*4;
  const int gcol = (c>>2)*1024 + j0 + (c&3);
  f32x4 acc = {0.f,0.f,0.f,0.f};
  for (int ch=0; ch<5; ++ch){
    for (int p=0; p<13; ++p){
      int e = p*256 + tid;         // 3328 16B chunks
      int row = e/52, k16 = e - row*52;
      *(short8*)((char*)As + row*848 + k16*16) =
        *(const short8*)(Adec + (size_t)row*2080 + ch*416 + k16*8);
    }
    for (int p=0; p<26; ++p){
      int e = p*256 + tid;         // 6656 elems
      int kl = e>>4, cc = e&15;
      int kg = ch*416 + kl;
      int col = (cc>>2)*1024 + j0 + (cc&3);
      float v;
      if (kg <= 1024) v = dec_k_[(size_t)kg*G4 + col];
      else if (kg <= 2048) v = dec_rk_[(size_t)(kg-1025)*G4 + col];
      else v = 0.f;
      Ws[kl*19 + cc] = f2bf(v);
    }
    __syncthreads();
    #pragma unroll
    for (int s=0; s<13; ++s){
      short8 af = *(const short8*)((const char*)As + (w*16+c)*848 + s*64 + koct*16);
      short8 bf;
      #pragma unroll
      for (int i=0; i<8; ++i) bf[i] = (short)Ws[(s*32 + koct*8 + i)*19 + c];
      acc = __builtin_amdgcn_mfma_f32_16x16x32_bf16(af, bf, acc, 0,0,0);
    }
    __syncthreads();
  }
  const float sbias = dec_b_[gcol];
  #pragma unroll
  for (int j=0; j<4; ++j)
    zex[(w*16 + koct*4 + j)*17 + c] = acc[j] + sbias;
  __syncthreads();
  {
    int b = tid&63, jj = tid>>6;
    float zi = zex[b*17 + jj], zf = zex[b*17+4+jj], zg = zex[b*17+8+jj], zo = zex[b*17+12+jj];
    float cold = cdec[(j0+jj)*BB + b];
    float cnew = sigm(zf)*cold + sigm(zi)*tanhfast(zg);
    float hnew = sigm(zo)*tanhfast(cnew);
    cdec[(j0+jj)*BB + b] = cnew;
    hdec[b*HH + j0 + jj] = f2bf(hnew);
  }
}

// ---------------- final y = h @ fin_w + fin_b (bf16 h) -----------------------
__global__ __launch_bounds__(256) void final_y(
  const u16* __restrict__ hdec, const float* __restrict__ fw,
  const float* __restrict__ fb, float* __restrict__ yprev,
  float* __restrict__ outy, int writeOut)
{
  __shared__ float red[256];
  const int b = blockIdx.x, tid = threadIdx.x;
  ushort4 hv = *(const ushort4*)(hdec + (size_t)b*HH + tid*4);
  float4 wv = *(const float4*)(fw + tid*4);
  red[tid] = bf2f(hv.x)*wv.x + bf2f(hv.y)*wv.y + bf2f(hv.z)*wv.z + bf2f(hv.w)*wv.w;
  __syncthreads();
  for (int sft=128; sft; sft>>=1){ if (tid<sft) red[tid] += red[tid+sft]; __syncthreads(); }
  if (tid==0){
    float y = red[0] + fb[0];
    yprev[b] = y;
    if (writeOut) outy[b] = y;
  }
}

__global__ void init_yprev(const float* __restrict__ x, float* __restrict__ yprev){
  int b = threadIdx.x;
  if (b < BB) yprev[b] = x[(size_t)b*TXX*DD + (size_t)(TXX-1)*DD + (DD-1)];
}

__global__ __launch_bounds__(256) void conv_w1(const float* __restrict__ w1, u16* __restrict__ w1b){
  int e = blockIdx.x*256 + threadIdx.x;   // 2048*512 / 256 = 4096 blocks
  w1b[e] = f2bf(w1[e]);
}

extern "C" void kernel_launch(void* const* d_in, const int* in_sizes, int n_in,
                              void* d_out, int out_size, void* d_ws, size_t ws_size,
                              hipStream_t stream)
{
  (void)in_sizes; (void)n_in; (void)out_size; (void)ws_size;
  const float* x      = (const float*)d_in[0];
  const float* enc_k  = (const float*)d_in[1];
  const float* enc_rk = (const float*)d_in[2];
  const float* enc_b  = (const float*)d_in[3];
  const float* dec_k  = (const float*)d_in[4];
  const float* dec_rk = (const float*)d_in[5];
  const float* dec_b  = (const float*)d_in[6];
  const float* att_w1 = (const float*)d_in[7];
  const float* att_b1 = (const float*)d_in[8];
  const float* att_w2 = (const float*)d_in[9];
  const float* att_b2 = (const float*)d_in[10];
  const float* fin_w  = (const float*)d_in[11];
  const float* fin_b  = (const float*)d_in[12];
  float* out = (float*)d_out;

  char* wsp = (char*)d_ws;
  u16*   yenc = (u16*)(wsp);                      // 67108864
  u16*   eenc = (u16*)(wsp + 67108864);           // 33554432
  u16*   w1b  = (u16*)(wsp + 100663296);          // 2097152
  u16*   hbuf = (u16*)(wsp + 102760448);          // 262144 (2 x 64x1024 bf16)
  u16*   Adec = (u16*)(wsp + 103022592);          // 266240
  float* cdec = (float*)(wsp + 103288832);        // 262144
  float* hW   = (float*)(wsp + 103550976);        // 131072
  float* e2   = (float*)(wsp + 103682048);        // 131072
  float* ctxb = (float*)(wsp + 103813120);        // 262144
  float* yprev= (float*)(wsp + 104075264);        // 256
  unsigned* bar=(unsigned*)(wsp + 104075520);     // 4096

  hipFuncSetAttribute((const void*)enc_persist, hipFuncAttributeMaxDynamicSharedMemorySize, 136448);
  hipFuncSetAttribute((const void*)hw_mfma,     hipFuncAttributeMaxDynamicSharedMemorySize, 86016);
  hipFuncSetAttribute((const void*)dec_mfma,    hipFuncAttributeMaxDynamicSharedMemorySize, 74432);

  hipMemsetAsync(hbuf, 0, 262144, stream);
  hipMemsetAsync(bar, 0, 4096, stream);
  init_yprev<<<1, 64, 0, stream>>>(x, yprev);
  conv_w1<<<4096, 256, 0, stream>>>(att_w1, w1b);

  enc_persist<<<256, 256, 136448, stream>>>(x, enc_k, enc_rk, enc_b, hbuf, yenc, cdec, bar);

  eenc_mfma<<<dim3(256,8), 256, 0, stream>>>(yenc, w1b, att_b1, eenc);

  u16* hdec = hbuf;   // final encoder h lives in hbuf[0]
  for (int s=0; s<TYY; ++s){
    int last = (s == TYY-1);
    hw_mfma  <<<32, 256, 86016, stream>>>(hdec, w1b, hW);
    att_scores<<<8192, 256, 0, stream>>>(eenc, hW, att_w2, att_b2, e2);
    att_softmax<<<64, 256, 0, stream>>>(e2, out, last);
    ctx_sum  <<<64, 256, 0, stream>>>(e2, yenc, ctxb);
    assemble_A<<<520, 256, 0, stream>>>(yprev, ctxb, hdec, Adec);
    dec_mfma <<<256, 256, 74432, stream>>>(Adec, dec_k, dec_rk, dec_b, cdec, hdec);
    final_y  <<<64, 256, 0, stream>>>(hdec, fin_w, fin_b, yprev, out, last);
  }
}

// Round 3
// 9209.563 us; speedup vs baseline: 4.5177x; 1.7556x over previous
//
#include <hip/hip_runtime.h>

#define BB 64
#define TXX 512
#define DD 64
#define HH 1024
#define UU 512
#define TYY 16
#define G4 4096

using u16 = unsigned short;
typedef __attribute__((ext_vector_type(8))) short short8;
typedef __attribute__((ext_vector_type(4))) float f32x4;

__device__ __forceinline__ float bf2f(u16 v){ return __uint_as_float(((unsigned)v)<<16); }
__device__ __forceinline__ u16 f2bf(float f){
  unsigned u = __float_as_uint(f);
  u += 0x7FFF + ((u>>16)&1);
  return (u16)(u>>16);
}
__device__ __forceinline__ float sigm(float x){
  x = fminf(fmaxf(x,-30.f),30.f);
  return 1.f/(1.f+__expf(-x));
}
__device__ __forceinline__ float tanhfast(float x){
  x = fminf(fmaxf(x,-15.f),15.f);
  float e = __expf(2.f*x);
  return (e-1.f)/(e+1.f);
}

// hardware transpose read: lane passes its own 8B-slot address
__device__ __forceinline__ unsigned long long tr16(unsigned addr){
  unsigned long long r;
  asm volatile("ds_read_b64_tr_b16 %0, %1" : "=v"(r) : "v"(addr));
  return r;
}

// ---------------- two-level monotonic grid barrier (256 blocks) --------------
__device__ __forceinline__ void gbar(unsigned* bar, int bid, unsigned bk){
  __syncthreads();
  if (threadIdx.x == 0){
    unsigned* cnt  = bar + (bid>>4)*32;   // 16 groups, 128B apart
    unsigned* root = bar + 512;
    unsigned* gen  = bar + 544;
    __threadfence();
    if (__hip_atomic_fetch_add(cnt, 1u, __ATOMIC_ACQ_REL, __HIP_MEMORY_SCOPE_AGENT) == bk*16u + 15u){
      if (__hip_atomic_fetch_add(root, 1u, __ATOMIC_ACQ_REL, __HIP_MEMORY_SCOPE_AGENT) == bk*16u + 15u){
        __hip_atomic_fetch_add(gen, 1u, __ATOMIC_ACQ_REL, __HIP_MEMORY_SCOPE_AGENT);
      } else {
        while (__hip_atomic_load(gen, __ATOMIC_RELAXED, __HIP_MEMORY_SCOPE_AGENT) <= bk)
          __builtin_amdgcn_s_sleep(2);
        (void)__hip_atomic_load(gen, __ATOMIC_ACQUIRE, __HIP_MEMORY_SCOPE_AGENT);
      }
    } else {
      while (__hip_atomic_load(gen, __ATOMIC_RELAXED, __HIP_MEMORY_SCOPE_AGENT) <= bk)
        __builtin_amdgcn_s_sleep(2);
      (void)__hip_atomic_load(gen, __ATOMIC_ACQUIRE, __HIP_MEMORY_SCOPE_AGENT);
    }
  }
  __syncthreads();
}

// ---------------- persistent encoder ----------------------------------------
// 256 blocks x 512 thr (8 waves = 4 b-groups x 2 K-halves). Block owns h-cols
// j0..j0+3 (16 z-cols). h history in yencT[t][g][hcol][b16] bf16 (block-exclusive
// full-line writes). LDS: linear 128KB stage + 2 x zex partial-sum planes.
__global__ __launch_bounds__(512, 2) void enc_persist(
    const float* __restrict__ x, const float* __restrict__ enc_k_,
    const float* __restrict__ enc_rk_, const float* __restrict__ enc_b_,
    u16* __restrict__ yencT, u16* __restrict__ hdec,
    float* __restrict__ cdec, unsigned* __restrict__ bar)
{
  extern __shared__ char smem[];                 // 131072 stage + 2*4352 zex
  float* zex0 = (float*)(smem + 131072);
  float* zex1 = (float*)(smem + 131072 + 4352);
  const int tid = threadIdx.x, bid = blockIdx.x;
  const int l = tid & 63;
  const int w = tid >> 6;       // 0..7
  const int g = w & 3;          // b-group (16 batches)
  const int half = w >> 2;      // K half (512 each)
  const int c = l & 15, koct = l >> 4;
  const int j0 = bid*4;
  const int gcol = (c>>2)*1024 + j0 + (c&3);     // zcol c -> (gate c>>2, hcol j0+(c&3))

  // recurrent weight B-fragments, k-order matched to tr-read permutation
  short8 bR[16];
  #pragma unroll
  for (int kk=0; kk<16; ++kk){
    short8 f;
    #pragma unroll
    for (int i=0; i<8; ++i){
      int k = half*512 + kk*32 + ((i<4) ? (koct*4+i) : (16 + koct*4 + (i-4)));
      f[i] = (short)f2bf(enc_rk_[(size_t)k*G4 + gcol]);
    }
    bR[kk] = f;
  }
  // x weights (standard k-order), used by half==0 waves
  short8 bK[2];
  #pragma unroll
  for (int kk=0; kk<2; ++kk){
    short8 f;
    #pragma unroll
    for (int i=0; i<8; ++i)
      f[i] = (short)f2bf(enc_k_[(size_t)(kk*32 + koct*8 + i)*G4 + gcol]);
    bK[kk] = f;
  }
  // gate-thread state (tid<256): thread <-> (batch gb, local hcol gj)
  float creg = 0.f;
  float bz0=0.f,bz1=0.f,bz2=0.f,bz3=0.f;
  const int gb = tid & 63, gj = tid >> 6;
  if (tid < 256){
    bz0 = enc_b_[0*1024 + j0 + gj];
    bz1 = enc_b_[1*1024 + j0 + gj];
    bz2 = enc_b_[2*1024 + j0 + gj];
    bz3 = enc_b_[3*1024 + j0 + gj];
  }
  const unsigned ldsbase = (unsigned)(size_t)(void*)smem;
  const unsigned trb = ldsbase + (unsigned)(g*32768 + half*16384 + l*8);

  for (int t=0; t<TXX; ++t){
    f32x4 acc = {0.f,0.f,0.f,0.f};
    // x contribution (independent of h) before the barrier
    if (half == 0){
      const float* xp = x + (size_t)(g*16 + c)*(TXX*DD) + (size_t)t*DD + koct*8;
      float4 v0 = *(const float4*)(xp);
      float4 v1 = *(const float4*)(xp+4);
      short8 ax;
      ax[0]=(short)f2bf(v0.x); ax[1]=(short)f2bf(v0.y);
      ax[2]=(short)f2bf(v0.z); ax[3]=(short)f2bf(v0.w);
      ax[4]=(short)f2bf(v1.x); ax[5]=(short)f2bf(v1.y);
      ax[6]=(short)f2bf(v1.z); ax[7]=(short)f2bf(v1.w);
      acc = __builtin_amdgcn_mfma_f32_16x16x32_bf16(ax, bK[0], acc, 0,0,0);
      float4 v2 = *(const float4*)(xp+32);
      float4 v3 = *(const float4*)(xp+36);
      short8 ax2;
      ax2[0]=(short)f2bf(v2.x); ax2[1]=(short)f2bf(v2.y);
      ax2[2]=(short)f2bf(v2.z); ax2[3]=(short)f2bf(v2.w);
      ax2[4]=(short)f2bf(v3.x); ax2[5]=(short)f2bf(v3.y);
      ax2[6]=(short)f2bf(v3.z); ax2[7]=(short)f2bf(v3.w);
      acc = __builtin_amdgcn_mfma_f32_16x16x32_bf16(ax2, bK[1], acc, 0,0,0);
    }
    if (t > 0){
      gbar(bar, bid, (unsigned)(t-1));
      // stage yencT[t-1] (128KB) linearly into LDS
      const short8* src = (const short8*)(yencT + (size_t)(t-1)*65536);
      short8* dst = (short8*)smem;
      #pragma unroll
      for (int p=0; p<16; ++p)
        dst[p*512 + tid] = src[p*512 + tid];
      __syncthreads();
      // K-half loop: hw-transpose A reads, software-pipelined depth 2
      unsigned a = trb;
      unsigned long long r0 = tr16(a), r1 = tr16(a + 512);
      unsigned long long n0 = 0, n1 = 0;
      #pragma unroll
      for (int kk=0; kk<16; ++kk){
        if (kk < 15){
          n0 = tr16(a + 1024); n1 = tr16(a + 1536);
          asm volatile("s_waitcnt lgkmcnt(2)" ::: "memory");
        } else {
          asm volatile("s_waitcnt lgkmcnt(0)" ::: "memory");
        }
        __builtin_amdgcn_sched_barrier(0);
        union { unsigned long long q[2]; short8 s; } u;
        u.q[0] = r0; u.q[1] = r1;
        acc = __builtin_amdgcn_mfma_f32_16x16x32_bf16(u.s, bR[kk], acc, 0,0,0);
        r0 = n0; r1 = n1; a += 1024;
      }
    }
    // publish partial sums
    {
      float* zx = half ? zex1 : zex0;
      #pragma unroll
      for (int j=0; j<4; ++j)
        zx[(g*16 + koct*4 + j)*17 + c] = acc[j];
    }
    __syncthreads();
    if (tid < 256){
      float zi = zex0[gb*17 +      gj] + zex1[gb*17 +      gj] + bz0;
      float zf = zex0[gb*17 +  4 + gj] + zex1[gb*17 +  4 + gj] + bz1;
      float zg = zex0[gb*17 +  8 + gj] + zex1[gb*17 +  8 + gj] + bz2;
      float zo = zex0[gb*17 + 12 + gj] + zex1[gb*17 + 12 + gj] + bz3;
      float cnew = sigm(zf)*creg + sigm(zi)*tanhfast(zg);
      float hnew = sigm(zo)*tanhfast(cnew);
      creg = cnew;
      u16 hb = f2bf(hnew);
      yencT[((size_t)(t*4 + (gb>>4))*1024 + j0 + gj)*16 + (gb&15)] = hb;
      if (t == TXX-1){
        hdec[(size_t)gb*HH + j0 + gj] = hb;
        cdec[(size_t)(j0+gj)*BB + gb] = cnew;
      }
    }
    // next iteration's zex writes are ordered behind gbar's __syncthreads()
  }
}

// ---------------- Eenc = y_enc @ w1b[:H] + b1 (bf16 out, MFMA, yencT input) --
// grid (256,8), 256 thr; M-tile = 2 t x 64 b (8 subtiles of 16b), N-tile 64
__global__ __launch_bounds__(256) void eenc_mfma(
    const u16* __restrict__ yencT, const u16* __restrict__ w1b,
    const float* __restrict__ b1, u16* __restrict__ eenc)
{
  __shared__ u16 As[4096];     // 8KB: [8 sub][32 k][16 b2]
  __shared__ u16 Bs[64*40];    // [col][40 pi-slots]
  const int tid = threadIdx.x;
  const int l = tid&63, wm = tid>>6;
  const int c = l&15, koct = l>>4;
  const int t0 = blockIdx.x*2, n0 = blockIdx.y*64;
  const unsigned ab = (unsigned)(size_t)(void*)As;
  f32x4 acc[2][4];
  #pragma unroll
  for (int a=0;a<2;++a)
    #pragma unroll
    for (int b=0;b<4;++b) acc[a][b] = (f32x4){0.f,0.f,0.f,0.f};

  for (int k0=0; k0<HH; k0+=32){
    #pragma unroll
    for (int p=0; p<2; ++p){
      int e = p*256 + tid;          // 512 chunks of 16B
      int sub = e>>6, w16 = e&63;
      const u16* gsrc = yencT + ((size_t)((t0 + (sub>>2))*4 + (sub&3))*1024 + k0)*16 + w16*8;
      *(short8*)((char*)As + e*16) = *(const short8*)gsrc;
    }
    #pragma unroll
    for (int p=0; p<8; ++p){
      int e = p*256 + tid;          // 2048 elems, pi-slotted transpose
      int kk = e>>6, col = e&63;
      int k2 = kk & 15;
      int slot = (k2>>2)*8 + ((kk&16)?4:0) + (k2&3);
      Bs[col*40 + slot] = w1b[(size_t)(k0+kk)*UU + n0 + col];
    }
    __syncthreads();
    unsigned long long r00 = tr16(ab + wm*1024 + l*8);
    unsigned long long r01 = tr16(ab + wm*1024 + 512 + l*8);
    unsigned long long r10 = tr16(ab + (wm+4)*1024 + l*8);
    unsigned long long r11 = tr16(ab + (wm+4)*1024 + 512 + l*8);
    asm volatile("s_waitcnt lgkmcnt(0)" ::: "memory");
    __builtin_amdgcn_sched_barrier(0);
    union { unsigned long long q[2]; short8 s; } u0, u1;
    u0.q[0]=r00; u0.q[1]=r01;
    u1.q[0]=r10; u1.q[1]=r11;
    #pragma unroll
    for (int nt=0; nt<4; ++nt){
      short8 bf = *(const short8*)((const char*)Bs + (nt*16+c)*80 + koct*16);
      acc[0][nt] = __builtin_amdgcn_mfma_f32_16x16x32_bf16(u0.s, bf, acc[0][nt], 0,0,0);
      acc[1][nt] = __builtin_amdgcn_mfma_f32_16x16x32_bf16(u1.s, bf, acc[1][nt], 0,0,0);
    }
    __syncthreads();
  }
  float sbn[4];
  #pragma unroll
  for (int nt=0; nt<4; ++nt) sbn[nt] = b1[n0 + nt*16 + c];
  #pragma unroll
  for (int s=0; s<2; ++s){
    int sub = wm + s*4;
    int t = t0 + (sub>>2), g = sub&3;
    #pragma unroll
    for (int nt=0; nt<4; ++nt){
      #pragma unroll
      for (int j=0; j<4; ++j){
        int b = g*16 + koct*4 + j;
        eenc[((size_t)b*TXX + t)*UU + n0 + nt*16 + c] = f2bf(acc[s][nt][j] + sbn[nt]);
      }
    }
  }
}

// ---------------- hW = h @ w1b[H:] (MFMA) ------------------------------------
__global__ __launch_bounds__(256) void hw_mfma(
    const u16* __restrict__ hdec, const u16* __restrict__ w1b,
    float* __restrict__ hW)
{
  extern __shared__ char smem[];
  u16* As = (u16*)smem;              // 64 x stride 520 u16 (1040 B) = 66560
  u16* Ws = (u16*)(smem + 66560);    // 512 x stride 19 u16 = 19456
  const int tid = threadIdx.x;
  const int l = tid&63, w = tid>>6;
  const int c = l&15, koct = l>>4;
  const int u0 = blockIdx.x*16;
  f32x4 acc = {0.f,0.f,0.f,0.f};
  for (int ch=0; ch<2; ++ch){
    #pragma unroll
    for (int p=0; p<16; ++p){
      int e = p*256 + tid;
      int row = e>>6, k16 = e&63;
      *(short8*)((char*)As + row*1040 + k16*16) =
        *(const short8*)(hdec + (size_t)row*HH + ch*512 + k16*8);
    }
    #pragma unroll
    for (int p=0; p<32; ++p){
      int e = p*256 + tid;
      int kk = e>>4, cc = e&15;
      Ws[kk*19 + cc] = w1b[(size_t)(HH + ch*512 + kk)*UU + u0 + cc];
    }
    __syncthreads();
    #pragma unroll
    for (int s=0; s<16; ++s){
      short8 af = *(const short8*)((const char*)As + (w*16+c)*1040 + s*64 + koct*16);
      short8 bf;
      #pragma unroll
      for (int i=0; i<8; ++i) bf[i] = (short)Ws[(s*32 + koct*8 + i)*19 + c];
      acc = __builtin_amdgcn_mfma_f32_16x16x32_bf16(af, bf, acc, 0,0,0);
    }
    __syncthreads();
  }
  #pragma unroll
  for (int j=0; j<4; ++j)
    hW[(size_t)(w*16 + koct*4 + j)*UU + u0 + c] = acc[j];
}

// ---------------- scores: e2 = relu( tanh(Eenc + hW) . w2 + b2 ) --------------
__global__ __launch_bounds__(256) void att_scores(
  const u16* __restrict__ eenc, const float* __restrict__ hW,
  const float* __restrict__ w2, const float* __restrict__ b2,
  float* __restrict__ e2)
{
  const int tid = threadIdx.x;
  const int lane = tid & 63;
  const int p = blockIdx.x*4 + (tid>>6);
  const int b = p >> 9;
  const int u0 = lane*8;
  uint4 ev = *reinterpret_cast<const uint4*>(eenc + (size_t)p*UU + u0);
  float4 hw0 = *reinterpret_cast<const float4*>(hW + (size_t)b*UU + u0);
  float4 hw1 = *reinterpret_cast<const float4*>(hW + (size_t)b*UU + u0 + 4);
  float4 w20 = *reinterpret_cast<const float4*>(w2 + u0);
  float4 w21 = *reinterpret_cast<const float4*>(w2 + u0 + 4);
  float sum;
  sum  = tanhfast(bf2f((u16)(ev.x & 0xffff)) + hw0.x) * w20.x;
  sum += tanhfast(bf2f((u16)(ev.x >> 16   )) + hw0.y) * w20.y;
  sum += tanhfast(bf2f((u16)(ev.y & 0xffff)) + hw0.z) * w20.z;
  sum += tanhfast(bf2f((u16)(ev.y >> 16   )) + hw0.w) * w20.w;
  sum += tanhfast(bf2f((u16)(ev.z & 0xffff)) + hw1.x) * w21.x;
  sum += tanhfast(bf2f((u16)(ev.z >> 16   )) + hw1.y) * w21.y;
  sum += tanhfast(bf2f((u16)(ev.w & 0xffff)) + hw1.z) * w21.z;
  sum += tanhfast(bf2f((u16)(ev.w >> 16   )) + hw1.w) * w21.w;
  #pragma unroll
  for (int off=32; off; off>>=1) sum += __shfl_down(sum, off);
  if (lane==0) e2[p] = fmaxf(sum + b2[0], 0.f);
}

// ---------------- softmax over t (in-place on e2) ----------------------------
__global__ __launch_bounds__(256) void att_softmax(
  float* __restrict__ e2, float* __restrict__ outw, int writeOut)
{
  __shared__ float red[256];
  const int b = blockIdx.x, tid = threadIdx.x;
  float v1 = e2[b*TXX + tid], v2 = e2[b*TXX + 256 + tid];
  red[tid] = fmaxf(v1,v2); __syncthreads();
  for (int sft=128; sft; sft>>=1){ if (tid<sft) red[tid] = fmaxf(red[tid], red[tid+sft]); __syncthreads(); }
  float m = red[0]; __syncthreads();
  float x1 = __expf(v1-m), x2 = __expf(v2-m);
  red[tid] = x1+x2; __syncthreads();
  for (int sft=128; sft; sft>>=1){ if (tid<sft) red[tid] += red[tid+sft]; __syncthreads(); }
  float inv = 1.f/red[0];
  float w1v = x1*inv, w2v = x2*inv;
  e2[b*TXX+tid] = w1v; e2[b*TXX+256+tid] = w2v;
  if (writeOut){
    outw[64 + b*TXX + tid] = w1v;
    outw[64 + b*TXX + 256 + tid] = w2v;
  }
}

// ---------------- ctx = sum_t w[t]*y_enc[b,t,:] (yencT input) ----------------
// grid 64 (16-h slices), 512 thr. e2 staged transposed in LDS (stride 65).
__global__ __launch_bounds__(512) void ctx_sum(
  const float* __restrict__ e2, const u16* __restrict__ yencT,
  float* __restrict__ ctx)
{
  extern __shared__ float wl[];     // [512 t][stride 65] f32
  const int tid = threadIdx.x;
  const int h0 = blockIdx.x*16;
  {
    int b = tid>>3, t0 = (tid&7)*64;
    for (int i=0; i<64; i+=4){
      float4 v = *(const float4*)(e2 + b*TXX + t0 + i);
      wl[(t0+i+0)*65 + b] = v.x; wl[(t0+i+1)*65 + b] = v.y;
      wl[(t0+i+2)*65 + b] = v.z; wl[(t0+i+3)*65 + b] = v.w;
    }
  }
  __syncthreads();
  const int b2 = tid&15, hh = (tid>>4)&15, gg = tid>>8;
  const int g0 = gg*2, g1 = g0+1;
  const int h = h0 + hh;
  float acc0=0.f, acc1=0.f;
  for (int t=0; t<TXX; ++t){
    float w0 = wl[t*65 + g0*16 + b2];
    float w1 = wl[t*65 + g1*16 + b2];
    u16 y0 = yencT[((size_t)(t*4+g0)*1024 + h)*16 + b2];
    u16 y1 = yencT[((size_t)(t*4+g1)*1024 + h)*16 + b2];
    acc0 = fmaf(w0, bf2f(y0), acc0);
    acc1 = fmaf(w1, bf2f(y1), acc1);
  }
  ctx[(size_t)(g0*16+b2)*HH + h] = acc0;
  ctx[(size_t)(g1*16+b2)*HH + h] = acc1;
}

// ---------------- assemble decoder A = [yprev | ctx | h | 0pad] bf16 ---------
__global__ __launch_bounds__(256) void assemble_A(
  const float* __restrict__ yprev, const float* __restrict__ ctx,
  const u16* __restrict__ hdec, u16* __restrict__ Adec)
{
  int e = blockIdx.x*256 + threadIdx.x;  // 520*256 = 133120 = 64*2080
  int b = e/2080, cc = e - b*2080;
  float v;
  if (cc == 0) v = yprev[b];
  else if (cc <= 1024) v = ctx[b*HH + cc-1];
  else if (cc <= 2048) v = bf2f(hdec[b*HH + cc-1025]);
  else v = 0.f;
  Adec[e] = f2bf(v);
}

// ---------------- decoder LSTM (MFMA), weights bf16-converted on the fly -----
__global__ __launch_bounds__(256) void dec_mfma(
    const u16* __restrict__ Adec, const float* __restrict__ dec_k_,
    const float* __restrict__ dec_rk_, const float* __restrict__ dec_b_,
    float* __restrict__ cdec, u16* __restrict__ hdec)
{
  extern __shared__ char smem[];
  u16* As = (u16*)smem;                    // 64 x 848 B = 54272
  u16* Ws = (u16*)(smem + 54272);          // 416 x stride 19 u16 = 15808
  float* zex = (float*)(smem + 54272 + 15808);  // 4352
  const int tid = threadIdx.x;
  const int l = tid&63, w = tid>>6;
  const int c = l&15, koct = l>>4;
  const int j0 = blockIdx.x*4;
  const int gcol = (c>>2)*1024 + j0 + (c&3);
  f32x4 acc = {0.f,0.f,0.f,0.f};
  for (int ch=0; ch<5; ++ch){
    for (int p=0; p<13; ++p){
      int e = p*256 + tid;
      int row = e/52, k16 = e - row*52;
      *(short8*)((char*)As + row*848 + k16*16) =
        *(const short8*)(Adec + (size_t)row*2080 + ch*416 + k16*8);
    }
    for (int p=0; p<26; ++p){
      int e = p*256 + tid;
      int kl = e>>4, cc = e&15;
      int kg = ch*416 + kl;
      int col = (cc>>2)*1024 + j0 + (cc&3);
      float v;
      if (kg <= 1024) v = dec_k_[(size_t)kg*G4 + col];
      else if (kg <= 2048) v = dec_rk_[(size_t)(kg-1025)*G4 + col];
      else v = 0.f;
      Ws[kl*19 + cc] = f2bf(v);
    }
    __syncthreads();
    #pragma unroll
    for (int s=0; s<13; ++s){
      short8 af = *(const short8*)((const char*)As + (w*16+c)*848 + s*64 + koct*16);
      short8 bf;
      #pragma unroll
      for (int i=0; i<8; ++i) bf[i] = (short)Ws[(s*32 + koct*8 + i)*19 + c];
      acc = __builtin_amdgcn_mfma_f32_16x16x32_bf16(af, bf, acc, 0,0,0);
    }
    __syncthreads();
  }
  const float sbias = dec_b_[gcol];
  #pragma unroll
  for (int j=0; j<4; ++j)
    zex[(w*16 + koct*4 + j)*17 + c] = acc[j] + sbias;
  __syncthreads();
  {
    int b = tid&63, jj = tid>>6;
    float zi = zex[b*17 + jj], zf = zex[b*17+4+jj], zg = zex[b*17+8+jj], zo = zex[b*17+12+jj];
    float cold = cdec[(j0+jj)*BB + b];
    float cnew = sigm(zf)*cold + sigm(zi)*tanhfast(zg);
    float hnew = sigm(zo)*tanhfast(cnew);
    cdec[(j0+jj)*BB + b] = cnew;
    hdec[b*HH + j0 + jj] = f2bf(hnew);
  }
}

// ---------------- final y = h @ fin_w + fin_b (bf16 h) -----------------------
__global__ __launch_bounds__(256) void final_y(
  const u16* __restrict__ hdec, const float* __restrict__ fw,
  const float* __restrict__ fb, float* __restrict__ yprev,
  float* __restrict__ outy, int writeOut)
{
  __shared__ float red[256];
  const int b = blockIdx.x, tid = threadIdx.x;
  ushort4 hv = *(const ushort4*)(hdec + (size_t)b*HH + tid*4);
  float4 wv = *(const float4*)(fw + tid*4);
  red[tid] = bf2f(hv.x)*wv.x + bf2f(hv.y)*wv.y + bf2f(hv.z)*wv.z + bf2f(hv.w)*wv.w;
  __syncthreads();
  for (int sft=128; sft; sft>>=1){ if (tid<sft) red[tid] += red[tid+sft]; __syncthreads(); }
  if (tid==0){
    float y = red[0] + fb[0];
    yprev[b] = y;
    if (writeOut) outy[b] = y;
  }
}

__global__ void init_yprev(const float* __restrict__ x, float* __restrict__ yprev){
  int b = threadIdx.x;
  if (b < BB) yprev[b] = x[(size_t)b*TXX*DD + (size_t)(TXX-1)*DD + (DD-1)];
}

__global__ __launch_bounds__(256) void conv_w1(const float* __restrict__ w1, u16* __restrict__ w1b){
  int e = blockIdx.x*256 + threadIdx.x;
  w1b[e] = f2bf(w1[e]);
}

extern "C" void kernel_launch(void* const* d_in, const int* in_sizes, int n_in,
                              void* d_out, int out_size, void* d_ws, size_t ws_size,
                              hipStream_t stream)
{
  (void)in_sizes; (void)n_in; (void)out_size; (void)ws_size;
  const float* x      = (const float*)d_in[0];
  const float* enc_k  = (const float*)d_in[1];
  const float* enc_rk = (const float*)d_in[2];
  const float* enc_b  = (const float*)d_in[3];
  const float* dec_k  = (const float*)d_in[4];
  const float* dec_rk = (const float*)d_in[5];
  const float* dec_b  = (const float*)d_in[6];
  const float* att_w1 = (const float*)d_in[7];
  const float* att_b1 = (const float*)d_in[8];
  const float* att_w2 = (const float*)d_in[9];
  const float* att_b2 = (const float*)d_in[10];
  const float* fin_w  = (const float*)d_in[11];
  const float* fin_b  = (const float*)d_in[12];
  float* out = (float*)d_out;

  char* wsp = (char*)d_ws;
  u16*   yencT = (u16*)(wsp);                     // 67108864  [512][4][1024][16]
  u16*   eenc  = (u16*)(wsp + 67108864);          // 33554432
  u16*   w1b   = (u16*)(wsp + 100663296);         // 2097152
  u16*   hdec  = (u16*)(wsp + 102760448);         // 131072
  u16*   Adec  = (u16*)(wsp + 102891520);         // 266240
  float* cdec  = (float*)(wsp + 103157760);       // 262144
  float* hW    = (float*)(wsp + 103419904);       // 131072
  float* e2    = (float*)(wsp + 103550976);       // 131072
  float* ctxb  = (float*)(wsp + 103682048);       // 262144
  float* yprev = (float*)(wsp + 103944192);       // 256
  unsigned* bar= (unsigned*)(wsp + 103944448);    // 4096

  hipFuncSetAttribute((const void*)enc_persist, hipFuncAttributeMaxDynamicSharedMemorySize, 139776);
  hipFuncSetAttribute((const void*)hw_mfma,     hipFuncAttributeMaxDynamicSharedMemorySize, 86016);
  hipFuncSetAttribute((const void*)dec_mfma,    hipFuncAttributeMaxDynamicSharedMemorySize, 74432);
  hipFuncSetAttribute((const void*)ctx_sum,     hipFuncAttributeMaxDynamicSharedMemorySize, 133120);

  hipMemsetAsync(bar, 0, 4096, stream);
  init_yprev<<<1, 64, 0, stream>>>(x, yprev);
  conv_w1<<<4096, 256, 0, stream>>>(att_w1, w1b);

  enc_persist<<<256, 512, 139776, stream>>>(x, enc_k, enc_rk, enc_b, yencT, hdec, cdec, bar);

  eenc_mfma<<<dim3(256,8), 256, 0, stream>>>(yencT, w1b, att_b1, eenc);

  for (int s=0; s<TYY; ++s){
    int last = (s == TYY-1);
    hw_mfma   <<<32, 256, 86016, stream>>>(hdec, w1b, hW);
    att_scores<<<8192, 256, 0, stream>>>(eenc, hW, att_w2, att_b2, e2);
    att_softmax<<<64, 256, 0, stream>>>(e2, out, last);
    ctx_sum   <<<64, 512, 133120, stream>>>(e2, yencT, ctxb);
    assemble_A<<<520, 256, 0, stream>>>(yprev, ctxb, hdec, Adec);
    dec_mfma  <<<256, 256, 74432, stream>>>(Adec, dec_k, dec_rk, dec_b, cdec, hdec);
    final_y   <<<64, 256, 0, stream>>>(hdec, fin_w, fin_b, yprev, out, last);
  }
}

// Round 4
// 6086.818 us; speedup vs baseline: 6.8355x; 1.5130x over previous
//
#include <hip/hip_runtime.h>

#define BB 64
#define TXX 512
#define DD 64
#define HH 1024
#define UU 512
#define TYY 16
#define G4 4096

using u16 = unsigned short;
typedef __attribute__((ext_vector_type(8))) short short8;
typedef __attribute__((ext_vector_type(4))) float f32x4;

__device__ __forceinline__ float bf2f(u16 v){ return __uint_as_float(((unsigned)v)<<16); }
__device__ __forceinline__ u16 f2bf(float f){
  unsigned u = __float_as_uint(f);
  u += 0x7FFF + ((u>>16)&1);
  return (u16)(u>>16);
}
__device__ __forceinline__ float sigm(float x){
  x = fminf(fmaxf(x,-30.f),30.f);
  return 1.f/(1.f+__expf(-x));
}
__device__ __forceinline__ float tanhfast(float x){
  x = fminf(fmaxf(x,-15.f),15.f);
  float e = __expf(2.f*x);
  return (e-1.f)/(e+1.f);
}

// hardware transpose read: lane passes its own 8B-slot address
__device__ __forceinline__ unsigned long long tr16(unsigned addr){
  unsigned long long r;
  asm volatile("ds_read_b64_tr_b16 %0, %1" : "=v"(r) : "v"(addr));
  return r;
}

// ---------------- per-group barrier (32 blocks per b-group) ------------------
__device__ __forceinline__ void gbar32(unsigned* bar, int bg, unsigned bk){
  __syncthreads();
  if (threadIdx.x == 0){
    unsigned* cnt = bar + bg*64;
    unsigned* gen = bar + bg*64 + 32;
    __threadfence();
    if (__hip_atomic_fetch_add(cnt, 1u, __ATOMIC_ACQ_REL, __HIP_MEMORY_SCOPE_AGENT) == bk*32u + 31u){
      __hip_atomic_fetch_add(gen, 1u, __ATOMIC_RELEASE, __HIP_MEMORY_SCOPE_AGENT);
    } else {
      while (__hip_atomic_load(gen, __ATOMIC_RELAXED, __HIP_MEMORY_SCOPE_AGENT) <= bk)
        __builtin_amdgcn_s_sleep(1);
      (void)__hip_atomic_load(gen, __ATOMIC_ACQUIRE, __HIP_MEMORY_SCOPE_AGENT);
    }
  }
  __syncthreads();
}

// ---------------- persistent encoder ----------------------------------------
// 128 blocks = 4 b-groups x 32 z-groups; 512 thr (8 waves split K 128 each).
// Block owns 16 b-rows x 32 h-cols (128 z-cols). Per-group 32-block barrier.
// LDS: 8 x 4KB wave-private h stage + zex[8][16][128] f32 = 96 KB.
__global__ __launch_bounds__(512, 2) void enc_persist(
    const float* __restrict__ x, const float* __restrict__ enc_k_,
    const float* __restrict__ enc_rk_, const float* __restrict__ enc_b_,
    u16* __restrict__ yencT, u16* __restrict__ hdec,
    float* __restrict__ cdec, u16* __restrict__ AdecA, unsigned* __restrict__ bar)
{
  extern __shared__ char smem[];                 // 32768 stage + 65536 zex
  float* zex = (float*)(smem + 32768);
  const int tid = threadIdx.x, bid = blockIdx.x;
  const int l = tid & 63, w = tid >> 6;
  const int c = l & 15, koct = l >> 4;
  const int bg = bid & 3, zg = bid >> 2;

  // recurrent weights for wave's K slice [w*128, w*128+128), tr16 k-perm
  short8 bR[32];
  #pragma unroll
  for (int kk=0; kk<4; ++kk){
    #pragma unroll
    for (int nt=0; nt<8; ++nt){
      short8 f;
      #pragma unroll
      for (int i=0; i<8; ++i){
        int k = w*128 + kk*32 + ((i<4) ? (koct*4+i) : (16 + koct*4 + (i-4)));
        int gcol = (nt>>1)*1024 + zg*32 + (nt&1)*16 + c;
        f[i] = (short)f2bf(enc_rk_[(size_t)k*G4 + gcol]);
      }
      bR[kk*8+nt] = f;
    }
  }
  // x weights (standard k-order), waves 0-1 only (K = w*32..w*32+31)
  short8 bK[8];
  if (w < 2){
    #pragma unroll
    for (int nt=0; nt<8; ++nt){
      short8 f;
      #pragma unroll
      for (int i=0; i<8; ++i){
        int gcol = (nt>>1)*1024 + zg*32 + (nt&1)*16 + c;
        f[i] = (short)f2bf(enc_k_[(size_t)(w*32 + koct*8 + i)*G4 + gcol]);
      }
      bK[nt] = f;
    }
  }
  // gate-thread state: thread <-> (b local = tid>>5, hc = tid&31)
  const int gb = tid >> 5, ghc = tid & 31;
  float bz[4];
  #pragma unroll
  for (int g4=0; g4<4; ++g4) bz[g4] = enc_b_[g4*1024 + zg*32 + ghc];
  float creg = 0.f;

  const unsigned ldsbase = (unsigned)(size_t)(void*)smem;

  for (int t=0; t<TXX; ++t){
    f32x4 acc[8];
    #pragma unroll
    for (int nt=0; nt<8; ++nt) acc[nt] = (f32x4){0.f,0.f,0.f,0.f};
    // x contribution before the barrier (waves 0-1)
    if (w < 2){
      const float* xp = x + (size_t)(bg*16 + c)*(TXX*DD) + (size_t)t*DD + w*32 + koct*8;
      float4 v0 = *(const float4*)(xp);
      float4 v1 = *(const float4*)(xp+4);
      short8 ax;
      ax[0]=(short)f2bf(v0.x); ax[1]=(short)f2bf(v0.y);
      ax[2]=(short)f2bf(v0.z); ax[3]=(short)f2bf(v0.w);
      ax[4]=(short)f2bf(v1.x); ax[5]=(short)f2bf(v1.y);
      ax[6]=(short)f2bf(v1.z); ax[7]=(short)f2bf(v1.w);
      #pragma unroll
      for (int nt=0; nt<8; ++nt)
        acc[nt] = __builtin_amdgcn_mfma_f32_16x16x32_bf16(ax, bK[nt], acc[nt], 0,0,0);
    }
    if (t > 0){
      gbar32(bar, bg, (unsigned)(t-1));
      // wave-private stage: 4KB slice of this b-group's h plane
      const short8* src = (const short8*)(yencT + ((size_t)((t-1)*4 + bg))*16384 + w*2048);
      short8* dst = (short8*)(smem + w*4096);
      #pragma unroll
      for (int p=0; p<4; ++p) dst[p*64 + l] = src[p*64 + l];
      asm volatile("s_waitcnt lgkmcnt(0)" ::: "memory");
      unsigned a = ldsbase + (unsigned)(w*4096 + l*8);
      unsigned long long r0,r1,r2,r3,r4,r5,r6,r7;
      r0=tr16(a);      r1=tr16(a+512);
      r2=tr16(a+1024); r3=tr16(a+1536);
      r4=tr16(a+2048); r5=tr16(a+2560);
      r6=tr16(a+3072); r7=tr16(a+3584);
      asm volatile("s_waitcnt lgkmcnt(0)" ::: "memory");
      __builtin_amdgcn_sched_barrier(0);
      union { unsigned long long q[2]; short8 s; } u;
      u.q[0]=r0; u.q[1]=r1;
      #pragma unroll
      for (int nt=0; nt<8; ++nt) acc[nt] = __builtin_amdgcn_mfma_f32_16x16x32_bf16(u.s, bR[0+nt], acc[nt], 0,0,0);
      u.q[0]=r2; u.q[1]=r3;
      #pragma unroll
      for (int nt=0; nt<8; ++nt) acc[nt] = __builtin_amdgcn_mfma_f32_16x16x32_bf16(u.s, bR[8+nt], acc[nt], 0,0,0);
      u.q[0]=r4; u.q[1]=r5;
      #pragma unroll
      for (int nt=0; nt<8; ++nt) acc[nt] = __builtin_amdgcn_mfma_f32_16x16x32_bf16(u.s, bR[16+nt], acc[nt], 0,0,0);
      u.q[0]=r6; u.q[1]=r7;
      #pragma unroll
      for (int nt=0; nt<8; ++nt) acc[nt] = __builtin_amdgcn_mfma_f32_16x16x32_bf16(u.s, bR[24+nt], acc[nt], 0,0,0);
    }
    // publish K-partials
    #pragma unroll
    for (int nt=0; nt<8; ++nt){
      #pragma unroll
      for (int j=0; j<4; ++j)
        zex[w*2048 + (koct*4+j)*128 + nt*16 + c] = acc[nt][j];
    }
    __syncthreads();
    // gates
    {
      float zsum[4];
      #pragma unroll
      for (int g4=0; g4<4; ++g4){
        float s2 = zex[gb*128 + g4*32 + ghc];
        #pragma unroll
        for (int ww=1; ww<8; ++ww) s2 += zex[ww*2048 + gb*128 + g4*32 + ghc];
        zsum[g4] = s2 + bz[g4];
      }
      float cnew = sigm(zsum[1])*creg + sigm(zsum[0])*tanhfast(zsum[2]);
      float hnew = sigm(zsum[3])*tanhfast(cnew);
      creg = cnew;
      u16 hb = f2bf(hnew);
      yencT[((size_t)(t*4 + bg)*1024 + zg*32 + ghc)*16 + gb] = hb;
      if (t == TXX-1){
        int bglob = bg*16 + gb;
        int col = zg*32 + ghc;
        hdec[(size_t)bglob*HH + col] = hb;
        cdec[(size_t)col*BB + bglob] = cnew;
        AdecA[(size_t)bglob*2080 + 1025 + col] = hb;
      }
    }
  }
}

// ---------------- Eenc = y_enc @ w1b[:H] + b1 (bf16 out, MFMA, yencT input) --
__global__ __launch_bounds__(256) void eenc_mfma(
    const u16* __restrict__ yencT, const u16* __restrict__ w1b,
    const float* __restrict__ b1, u16* __restrict__ eenc)
{
  __shared__ u16 As[4096];     // 8KB: [8 sub][32 k][16 b2]
  __shared__ u16 Bs[64*40];    // [col][40 pi-slots]
  const int tid = threadIdx.x;
  const int l = tid&63, wm = tid>>6;
  const int c = l&15, koct = l>>4;
  const int t0 = blockIdx.x*2, n0 = blockIdx.y*64;
  const unsigned ab = (unsigned)(size_t)(void*)As;
  f32x4 acc[2][4];
  #pragma unroll
  for (int a=0;a<2;++a)
    #pragma unroll
    for (int b=0;b<4;++b) acc[a][b] = (f32x4){0.f,0.f,0.f,0.f};

  for (int k0=0; k0<HH; k0+=32){
    #pragma unroll
    for (int p=0; p<2; ++p){
      int e = p*256 + tid;
      int sub = e>>6, w16 = e&63;
      const u16* gsrc = yencT + ((size_t)((t0 + (sub>>2))*4 + (sub&3))*1024 + k0)*16 + w16*8;
      *(short8*)((char*)As + e*16) = *(const short8*)gsrc;
    }
    #pragma unroll
    for (int p=0; p<8; ++p){
      int e = p*256 + tid;
      int kk = e>>6, col = e&63;
      int k2 = kk & 15;
      int slot = (k2>>2)*8 + ((kk&16)?4:0) + (k2&3);
      Bs[col*40 + slot] = w1b[(size_t)(k0+kk)*UU + n0 + col];
    }
    __syncthreads();
    unsigned long long r00 = tr16(ab + wm*1024 + l*8);
    unsigned long long r01 = tr16(ab + wm*1024 + 512 + l*8);
    unsigned long long r10 = tr16(ab + (wm+4)*1024 + l*8);
    unsigned long long r11 = tr16(ab + (wm+4)*1024 + 512 + l*8);
    asm volatile("s_waitcnt lgkmcnt(0)" ::: "memory");
    __builtin_amdgcn_sched_barrier(0);
    union { unsigned long long q[2]; short8 s; } u0, u1;
    u0.q[0]=r00; u0.q[1]=r01;
    u1.q[0]=r10; u1.q[1]=r11;
    #pragma unroll
    for (int nt=0; nt<4; ++nt){
      short8 bf = *(const short8*)((const char*)Bs + (nt*16+c)*80 + koct*16);
      acc[0][nt] = __builtin_amdgcn_mfma_f32_16x16x32_bf16(u0.s, bf, acc[0][nt], 0,0,0);
      acc[1][nt] = __builtin_amdgcn_mfma_f32_16x16x32_bf16(u1.s, bf, acc[1][nt], 0,0,0);
    }
    __syncthreads();
  }
  float sbn[4];
  #pragma unroll
  for (int nt=0; nt<4; ++nt) sbn[nt] = b1[n0 + nt*16 + c];
  #pragma unroll
  for (int s=0; s<2; ++s){
    int sub = wm + s*4;
    int t = t0 + (sub>>2), g = sub&3;
    #pragma unroll
    for (int nt=0; nt<4; ++nt){
      #pragma unroll
      for (int j=0; j<4; ++j){
        int b = g*16 + koct*4 + j;
        eenc[((size_t)b*TXX + t)*UU + n0 + nt*16 + c] = f2bf(acc[s][nt][j] + sbn[nt]);
      }
    }
  }
}

// ---------------- hW = h @ w1b[H:] (MFMA) ------------------------------------
__global__ __launch_bounds__(256) void hw_mfma(
    const u16* __restrict__ hdec, const u16* __restrict__ w1b,
    float* __restrict__ hW)
{
  extern __shared__ char smem[];
  u16* As = (u16*)smem;              // 64 x stride 520 u16 (1040 B) = 66560
  u16* Ws = (u16*)(smem + 66560);    // 512 x stride 19 u16 = 19456
  const int tid = threadIdx.x;
  const int l = tid&63, w = tid>>6;
  const int c = l&15, koct = l>>4;
  const int u0 = blockIdx.x*16;
  f32x4 acc = {0.f,0.f,0.f,0.f};
  for (int ch=0; ch<2; ++ch){
    #pragma unroll
    for (int p=0; p<16; ++p){
      int e = p*256 + tid;
      int row = e>>6, k16 = e&63;
      *(short8*)((char*)As + row*1040 + k16*16) =
        *(const short8*)(hdec + (size_t)row*HH + ch*512 + k16*8);
    }
    #pragma unroll
    for (int p=0; p<32; ++p){
      int e = p*256 + tid;
      int kk = e>>4, cc = e&15;
      Ws[kk*19 + cc] = w1b[(size_t)(HH + ch*512 + kk)*UU + u0 + cc];
    }
    __syncthreads();
    #pragma unroll
    for (int s=0; s<16; ++s){
      short8 af = *(const short8*)((const char*)As + (w*16+c)*1040 + s*64 + koct*16);
      short8 bf;
      #pragma unroll
      for (int i=0; i<8; ++i) bf[i] = (short)Ws[(s*32 + koct*8 + i)*19 + c];
      acc = __builtin_amdgcn_mfma_f32_16x16x32_bf16(af, bf, acc, 0,0,0);
    }
    __syncthreads();
  }
  #pragma unroll
  for (int j=0; j<4; ++j)
    hW[(size_t)(w*16 + koct*4 + j)*UU + u0 + c] = acc[j];
}

// ---------------- scores: e2 = relu( tanh(Eenc + hW) . w2 + b2 ) --------------
__global__ __launch_bounds__(256) void att_scores(
  const u16* __restrict__ eenc, const float* __restrict__ hW,
  const float* __restrict__ w2, const float* __restrict__ b2,
  float* __restrict__ e2)
{
  const int tid = threadIdx.x;
  const int lane = tid & 63;
  const int p = blockIdx.x*4 + (tid>>6);
  const int b = p >> 9;
  const int u0 = lane*8;
  uint4 ev = *reinterpret_cast<const uint4*>(eenc + (size_t)p*UU + u0);
  float4 hw0 = *reinterpret_cast<const float4*>(hW + (size_t)b*UU + u0);
  float4 hw1 = *reinterpret_cast<const float4*>(hW + (size_t)b*UU + u0 + 4);
  float4 w20 = *reinterpret_cast<const float4*>(w2 + u0);
  float4 w21 = *reinterpret_cast<const float4*>(w2 + u0 + 4);
  float sum;
  sum  = tanhfast(bf2f((u16)(ev.x & 0xffff)) + hw0.x) * w20.x;
  sum += tanhfast(bf2f((u16)(ev.x >> 16   )) + hw0.y) * w20.y;
  sum += tanhfast(bf2f((u16)(ev.y & 0xffff)) + hw0.z) * w20.z;
  sum += tanhfast(bf2f((u16)(ev.y >> 16   )) + hw0.w) * w20.w;
  sum += tanhfast(bf2f((u16)(ev.z & 0xffff)) + hw1.x) * w21.x;
  sum += tanhfast(bf2f((u16)(ev.z >> 16   )) + hw1.y) * w21.y;
  sum += tanhfast(bf2f((u16)(ev.w & 0xffff)) + hw1.z) * w21.z;
  sum += tanhfast(bf2f((u16)(ev.w >> 16   )) + hw1.w) * w21.w;
  #pragma unroll
  for (int off=32; off; off>>=1) sum += __shfl_down(sum, off);
  if (lane==0) e2[p] = fmaxf(sum + b2[0], 0.f);
}

// ---------------- softmax over t (in-place on e2) ----------------------------
__global__ __launch_bounds__(256) void att_softmax(
  float* __restrict__ e2, float* __restrict__ outw, int writeOut)
{
  __shared__ float red[256];
  const int b = blockIdx.x, tid = threadIdx.x;
  float v1 = e2[b*TXX + tid], v2 = e2[b*TXX + 256 + tid];
  red[tid] = fmaxf(v1,v2); __syncthreads();
  for (int sft=128; sft; sft>>=1){ if (tid<sft) red[tid] = fmaxf(red[tid], red[tid+sft]); __syncthreads(); }
  float m = red[0]; __syncthreads();
  float x1 = __expf(v1-m), x2 = __expf(v2-m);
  red[tid] = x1+x2; __syncthreads();
  for (int sft=128; sft; sft>>=1){ if (tid<sft) red[tid] += red[tid+sft]; __syncthreads(); }
  float inv = 1.f/red[0];
  float w1v = x1*inv, w2v = x2*inv;
  e2[b*TXX+tid] = w1v; e2[b*TXX+256+tid] = w2v;
  if (writeOut){
    outw[64 + b*TXX + tid] = w1v;
    outw[64 + b*TXX + 256 + tid] = w2v;
  }
}

// ---------------- ctx: weighted sum over t, written bf16 into Adec cols 1..1024
__global__ __launch_bounds__(512) void ctx_sum(
  const float* __restrict__ e2, const u16* __restrict__ yencT,
  u16* __restrict__ Adec)
{
  extern __shared__ float wl[];     // [512 t][stride 65] f32
  const int tid = threadIdx.x;
  const int h0 = blockIdx.x*16;
  {
    int b = tid>>3, t0 = (tid&7)*64;
    for (int i=0; i<64; i+=4){
      float4 v = *(const float4*)(e2 + b*TXX + t0 + i);
      wl[(t0+i+0)*65 + b] = v.x; wl[(t0+i+1)*65 + b] = v.y;
      wl[(t0+i+2)*65 + b] = v.z; wl[(t0+i+3)*65 + b] = v.w;
    }
  }
  __syncthreads();
  const int b2 = tid&15, hh = (tid>>4)&15, gg = tid>>8;
  const int g0 = gg*2, g1 = g0+1;
  const int h = h0 + hh;
  float acc0=0.f, acc1=0.f;
  for (int t=0; t<TXX; ++t){
    float w0 = wl[t*65 + g0*16 + b2];
    float w1 = wl[t*65 + g1*16 + b2];
    u16 y0 = yencT[((size_t)(t*4+g0)*1024 + h)*16 + b2];
    u16 y1 = yencT[((size_t)(t*4+g1)*1024 + h)*16 + b2];
    acc0 = fmaf(w0, bf2f(y0), acc0);
    acc1 = fmaf(w1, bf2f(y1), acc1);
  }
  Adec[(size_t)(g0*16+b2)*2080 + 1 + h] = f2bf(acc0);
  Adec[(size_t)(g1*16+b2)*2080 + 1 + h] = f2bf(acc1);
}

// ---------------- decoder LSTM (MFMA); h written into NEXT step's Adec -------
__global__ __launch_bounds__(256) void dec_mfma(
    const u16* __restrict__ Adec, const float* __restrict__ dec_k_,
    const float* __restrict__ dec_rk_, const float* __restrict__ dec_b_,
    float* __restrict__ cdec, u16* __restrict__ hdec, u16* __restrict__ Anxt)
{
  extern __shared__ char smem[];
  u16* As = (u16*)smem;                    // 64 x 848 B = 54272
  u16* Ws = (u16*)(smem + 54272);          // 416 x stride 19 u16 = 15808
  float* zex = (float*)(smem + 54272 + 15808);  // 4352
  const int tid = threadIdx.x;
  const int l = tid&63, w = tid>>6;
  const int c = l&15, koct = l>>4;
  const int j0 = blockIdx.x*4;
  const int gcol = (c>>2)*1024 + j0 + (c&3);
  f32x4 acc = {0.f,0.f,0.f,0.f};
  for (int ch=0; ch<5; ++ch){
    for (int p=0; p<13; ++p){
      int e = p*256 + tid;
      int row = e/52, k16 = e - row*52;
      *(short8*)((char*)As + row*848 + k16*16) =
        *(const short8*)(Adec + (size_t)row*2080 + ch*416 + k16*8);
    }
    for (int p=0; p<26; ++p){
      int e = p*256 + tid;
      int kl = e>>4, cc = e&15;
      int kg = ch*416 + kl;
      int col = (cc>>2)*1024 + j0 + (cc&3);
      float v;
      if (kg <= 1024) v = dec_k_[(size_t)kg*G4 + col];
      else if (kg <= 2048) v = dec_rk_[(size_t)(kg-1025)*G4 + col];
      else v = 0.f;
      Ws[kl*19 + cc] = f2bf(v);
    }
    __syncthreads();
    #pragma unroll
    for (int s=0; s<13; ++s){
      short8 af = *(const short8*)((const char*)As + (w*16+c)*848 + s*64 + koct*16);
      short8 bf;
      #pragma unroll
      for (int i=0; i<8; ++i) bf[i] = (short)Ws[(s*32 + koct*8 + i)*19 + c];
      acc = __builtin_amdgcn_mfma_f32_16x16x32_bf16(af, bf, acc, 0,0,0);
    }
    __syncthreads();
  }
  const float sbias = dec_b_[gcol];
  #pragma unroll
  for (int j=0; j<4; ++j)
    zex[(w*16 + koct*4 + j)*17 + c] = acc[j] + sbias;
  __syncthreads();
  {
    int b = tid&63, jj = tid>>6;
    float zi = zex[b*17 + jj], zf = zex[b*17+4+jj], zg = zex[b*17+8+jj], zo = zex[b*17+12+jj];
    float cold = cdec[(j0+jj)*BB + b];
    float cnew = sigm(zf)*cold + sigm(zi)*tanhfast(zg);
    float hnew = sigm(zo)*tanhfast(cnew);
    cdec[(j0+jj)*BB + b] = cnew;
    u16 hb = f2bf(hnew);
    hdec[b*HH + j0 + jj] = hb;
    Anxt[(size_t)b*2080 + 1025 + j0 + jj] = hb;
  }
}

// ---------------- final y = h @ fin_w + fin_b (bf16 h) -----------------------
__global__ __launch_bounds__(256) void final_y(
  const u16* __restrict__ hdec, const float* __restrict__ fw,
  const float* __restrict__ fb, float* __restrict__ yprev,
  u16* __restrict__ Anxt, float* __restrict__ outy, int writeOut)
{
  __shared__ float red[256];
  const int b = blockIdx.x, tid = threadIdx.x;
  ushort4 hv = *(const ushort4*)(hdec + (size_t)b*HH + tid*4);
  float4 wv = *(const float4*)(fw + tid*4);
  red[tid] = bf2f(hv.x)*wv.x + bf2f(hv.y)*wv.y + bf2f(hv.z)*wv.z + bf2f(hv.w)*wv.w;
  __syncthreads();
  for (int sft=128; sft; sft>>=1){ if (tid<sft) red[tid] += red[tid+sft]; __syncthreads(); }
  if (tid==0){
    float y = red[0] + fb[0];
    yprev[b] = y;
    Anxt[(size_t)b*2080] = f2bf(y);
    if (writeOut) outy[b] = y;
  }
}

__global__ void init_yprev(const float* __restrict__ x, float* __restrict__ yprev,
                           u16* __restrict__ AdecA){
  int b = threadIdx.x;
  if (b < BB){
    float v = x[(size_t)b*TXX*DD + (size_t)(TXX-1)*DD + (DD-1)];
    yprev[b] = v;
    AdecA[(size_t)b*2080] = f2bf(v);
  }
}

__global__ __launch_bounds__(256) void conv_w1(const float* __restrict__ w1, u16* __restrict__ w1b){
  int e = blockIdx.x*256 + threadIdx.x;
  w1b[e] = f2bf(w1[e]);
}

extern "C" void kernel_launch(void* const* d_in, const int* in_sizes, int n_in,
                              void* d_out, int out_size, void* d_ws, size_t ws_size,
                              hipStream_t stream)
{
  (void)in_sizes; (void)n_in; (void)out_size; (void)ws_size;
  const float* x      = (const float*)d_in[0];
  const float* enc_k  = (const float*)d_in[1];
  const float* enc_rk = (const float*)d_in[2];
  const float* enc_b  = (const float*)d_in[3];
  const float* dec_k  = (const float*)d_in[4];
  const float* dec_rk = (const float*)d_in[5];
  const float* dec_b  = (const float*)d_in[6];
  const float* att_w1 = (const float*)d_in[7];
  const float* att_b1 = (const float*)d_in[8];
  const float* att_w2 = (const float*)d_in[9];
  const float* att_b2 = (const float*)d_in[10];
  const float* fin_w  = (const float*)d_in[11];
  const float* fin_b  = (const float*)d_in[12];
  float* out = (float*)d_out;

  char* wsp = (char*)d_ws;
  u16*   yencT = (u16*)(wsp);                     // 67108864  [512][4][1024][16]
  u16*   eenc  = (u16*)(wsp + 67108864);          // 33554432
  u16*   w1b   = (u16*)(wsp + 100663296);         // 2097152
  u16*   hdec  = (u16*)(wsp + 102760448);         // 131072
  u16*   AdecA = (u16*)(wsp + 102891520);         // 266240
  u16*   AdecB = (u16*)(wsp + 103157760);         // 266240
  float* cdec  = (float*)(wsp + 103424000);       // 262144
  float* hW    = (float*)(wsp + 103686144);       // 131072
  float* e2    = (float*)(wsp + 103817216);       // 131072
  float* yprev = (float*)(wsp + 103948288);       // 256
  unsigned* bar= (unsigned*)(wsp + 103948544);    // 4096

  hipFuncSetAttribute((const void*)enc_persist, hipFuncAttributeMaxDynamicSharedMemorySize, 98304);
  hipFuncSetAttribute((const void*)hw_mfma,     hipFuncAttributeMaxDynamicSharedMemorySize, 86016);
  hipFuncSetAttribute((const void*)dec_mfma,    hipFuncAttributeMaxDynamicSharedMemorySize, 74432);
  hipFuncSetAttribute((const void*)ctx_sum,     hipFuncAttributeMaxDynamicSharedMemorySize, 133120);

  hipMemsetAsync(bar, 0, 4096, stream);
  init_yprev<<<1, 64, 0, stream>>>(x, yprev, AdecA);
  conv_w1<<<4096, 256, 0, stream>>>(att_w1, w1b);

  enc_persist<<<128, 512, 98304, stream>>>(x, enc_k, enc_rk, enc_b, yencT, hdec, cdec, AdecA, bar);

  eenc_mfma<<<dim3(256,8), 256, 0, stream>>>(yencT, w1b, att_b1, eenc);

  for (int s=0; s<TYY; ++s){
    int last = (s == TYY-1);
    u16* Acur = (s&1)? AdecB : AdecA;
    u16* Anxt = (s&1)? AdecA : AdecB;
    hw_mfma   <<<32, 256, 86016, stream>>>(hdec, w1b, hW);
    att_scores<<<8192, 256, 0, stream>>>(eenc, hW, att_w2, att_b2, e2);
    att_softmax<<<64, 256, 0, stream>>>(e2, out, last);
    ctx_sum   <<<64, 512, 133120, stream>>>(e2, yencT, Acur);
    dec_mfma  <<<256, 256, 74432, stream>>>(Acur, dec_k, dec_rk, dec_b, cdec, hdec, Anxt);
    final_y   <<<64, 256, 0, stream>>>(hdec, fin_w, fin_b, yprev, Anxt, out, last);
  }
}

// Round 5
// 5616.497 us; speedup vs baseline: 7.4079x; 1.0837x over previous
//
#include <hip/hip_runtime.h>

#define BB 64
#define TXX 512
#define DD 64
#define HH 1024
#define UU 512
#define TYY 16
#define G4 4096

using u16 = unsigned short;
typedef __attribute__((ext_vector_type(8))) short short8;
typedef __attribute__((ext_vector_type(4))) float f32x4;

__device__ __forceinline__ float bf2f(u16 v){ return __uint_as_float(((unsigned)v)<<16); }
__device__ __forceinline__ u16 f2bf(float f){
  unsigned u = __float_as_uint(f);
  u += 0x7FFF + ((u>>16)&1);
  return (u16)(u>>16);
}
__device__ __forceinline__ float sigm(float x){
  x = fminf(fmaxf(x,-30.f),30.f);
  return 1.f/(1.f+__expf(-x));
}
__device__ __forceinline__ float tanhfast(float x){
  x = fminf(fmaxf(x,-15.f),15.f);
  float e = __expf(2.f*x);
  return (e-1.f)/(e+1.f);
}

__device__ __forceinline__ unsigned long long tr16(unsigned addr){
  unsigned long long r;
  asm volatile("ds_read_b64_tr_b16 %0, %1" : "=v"(r) : "v"(addr));
  return r;
}

// ---------------- per-group barrier (32 blocks per b-group) ------------------
__device__ __forceinline__ void gbar32(unsigned* bar, int bg, unsigned bk){
  __syncthreads();
  if (threadIdx.x == 0){
    unsigned* cnt = bar + bg*64;
    unsigned* gen = bar + bg*64 + 32;
    __threadfence();
    if (__hip_atomic_fetch_add(cnt, 1u, __ATOMIC_ACQ_REL, __HIP_MEMORY_SCOPE_AGENT) == bk*32u + 31u){
      __hip_atomic_fetch_add(gen, 1u, __ATOMIC_RELEASE, __HIP_MEMORY_SCOPE_AGENT);
    } else {
      while (__hip_atomic_load(gen, __ATOMIC_RELAXED, __HIP_MEMORY_SCOPE_AGENT) <= bk)
        __builtin_amdgcn_s_sleep(1);
      (void)__hip_atomic_load(gen, __ATOMIC_ACQUIRE, __HIP_MEMORY_SCOPE_AGENT);
    }
  }
  __syncthreads();
}

// ---------------- persistent encoder ----------------------------------------
// 128 blocks; group bg = 2-XCD pair via (bid&7)>>1; zg = (bid&1)*16 + bid>>3.
// Block owns 16 b-rows x 32 h-cols (128 z-cols). 512 thr = 8 waves (K=128 each).
// LDS: 8 x 4KB wave-private h stage + zex 8 x [16][132] f32 = 100352 B.
__global__ __launch_bounds__(512, 2) void enc_persist(
    const float* __restrict__ x, const float* __restrict__ enc_k_,
    const float* __restrict__ enc_rk_, const float* __restrict__ enc_b_,
    u16* __restrict__ yencT, u16* __restrict__ hdec,
    float* __restrict__ cdec, u16* __restrict__ AdecA, unsigned* __restrict__ bar)
{
  extern __shared__ char smem[];
  float* zex = (float*)(smem + 32768);
  const int tid = threadIdx.x, bid = blockIdx.x;
  const int l = tid & 63, w = tid >> 6;
  const int c = l & 15, koct = l >> 4;
  const int xcd = bid & 7;
  const int bg = xcd >> 1;
  const int zg = (xcd & 1)*16 + (bid >> 3);

  short8 bR[32];
  #pragma unroll
  for (int kk=0; kk<4; ++kk){
    #pragma unroll
    for (int nt=0; nt<8; ++nt){
      short8 f;
      #pragma unroll
      for (int i=0; i<8; ++i){
        int k = w*128 + kk*32 + ((i<4) ? (koct*4+i) : (16 + koct*4 + (i-4)));
        int gcol = (nt>>1)*1024 + zg*32 + (nt&1)*16 + c;
        f[i] = (short)f2bf(enc_rk_[(size_t)k*G4 + gcol]);
      }
      bR[kk*8+nt] = f;
    }
  }
  short8 bK[8];
  if (w < 2){
    #pragma unroll
    for (int nt=0; nt<8; ++nt){
      short8 f;
      #pragma unroll
      for (int i=0; i<8; ++i){
        int gcol = (nt>>1)*1024 + zg*32 + (nt&1)*16 + c;
        f[i] = (short)f2bf(enc_k_[(size_t)(w*32 + koct*8 + i)*G4 + gcol]);
      }
      bK[nt] = f;
    }
  }
  const int gb = tid >> 5, ghc = tid & 31;
  float bz[4];
  #pragma unroll
  for (int g4=0; g4<4; ++g4) bz[g4] = enc_b_[g4*1024 + zg*32 + ghc];
  float creg = 0.f;

  const unsigned ldsbase = (unsigned)(size_t)(void*)smem;

  for (int t=0; t<TXX; ++t){
    f32x4 acc[8];
    #pragma unroll
    for (int nt=0; nt<8; ++nt) acc[nt] = (f32x4){0.f,0.f,0.f,0.f};
    if (w < 2){
      const float* xp = x + (size_t)(bg*16 + c)*(TXX*DD) + (size_t)t*DD + w*32 + koct*8;
      float4 v0 = *(const float4*)(xp);
      float4 v1 = *(const float4*)(xp+4);
      short8 ax;
      ax[0]=(short)f2bf(v0.x); ax[1]=(short)f2bf(v0.y);
      ax[2]=(short)f2bf(v0.z); ax[3]=(short)f2bf(v0.w);
      ax[4]=(short)f2bf(v1.x); ax[5]=(short)f2bf(v1.y);
      ax[6]=(short)f2bf(v1.z); ax[7]=(short)f2bf(v1.w);
      #pragma unroll
      for (int nt=0; nt<8; ++nt)
        acc[nt] = __builtin_amdgcn_mfma_f32_16x16x32_bf16(ax, bK[nt], acc[nt], 0,0,0);
    }
    if (t > 0){
      gbar32(bar, bg, (unsigned)(t-1));
      const short8* src = (const short8*)(yencT + ((size_t)((t-1)*4 + bg))*16384 + w*2048);
      short8* dst = (short8*)(smem + w*4096);
      #pragma unroll
      for (int p=0; p<4; ++p) dst[p*64 + l] = src[p*64 + l];
      asm volatile("s_waitcnt lgkmcnt(0)" ::: "memory");
      unsigned a = ldsbase + (unsigned)(w*4096 + l*8);
      unsigned long long r0,r1,r2,r3,r4,r5,r6,r7;
      r0=tr16(a);      r1=tr16(a+512);
      r2=tr16(a+1024); r3=tr16(a+1536);
      r4=tr16(a+2048); r5=tr16(a+2560);
      r6=tr16(a+3072); r7=tr16(a+3584);
      asm volatile("s_waitcnt lgkmcnt(0)" ::: "memory");
      __builtin_amdgcn_sched_barrier(0);
      union { unsigned long long q[2]; short8 s; } u;
      u.q[0]=r0; u.q[1]=r1;
      #pragma unroll
      for (int nt=0; nt<8; ++nt) acc[nt] = __builtin_amdgcn_mfma_f32_16x16x32_bf16(u.s, bR[0+nt], acc[nt], 0,0,0);
      u.q[0]=r2; u.q[1]=r3;
      #pragma unroll
      for (int nt=0; nt<8; ++nt) acc[nt] = __builtin_amdgcn_mfma_f32_16x16x32_bf16(u.s, bR[8+nt], acc[nt], 0,0,0);
      u.q[0]=r4; u.q[1]=r5;
      #pragma unroll
      for (int nt=0; nt<8; ++nt) acc[nt] = __builtin_amdgcn_mfma_f32_16x16x32_bf16(u.s, bR[16+nt], acc[nt], 0,0,0);
      u.q[0]=r6; u.q[1]=r7;
      #pragma unroll
      for (int nt=0; nt<8; ++nt) acc[nt] = __builtin_amdgcn_mfma_f32_16x16x32_bf16(u.s, bR[24+nt], acc[nt], 0,0,0);
    }
    #pragma unroll
    for (int nt=0; nt<8; ++nt){
      #pragma unroll
      for (int j=0; j<4; ++j)
        zex[w*2112 + (koct*4+j)*132 + nt*16 + c] = acc[nt][j];
    }
    __syncthreads();
    {
      float zsum[4];
      #pragma unroll
      for (int g4=0; g4<4; ++g4){
        float s2 = zex[gb*132 + g4*32 + ghc];
        #pragma unroll
        for (int ww=1; ww<8; ++ww) s2 += zex[ww*2112 + gb*132 + g4*32 + ghc];
        zsum[g4] = s2 + bz[g4];
      }
      float cnew = sigm(zsum[1])*creg + sigm(zsum[0])*tanhfast(zsum[2]);
      float hnew = sigm(zsum[3])*tanhfast(cnew);
      creg = cnew;
      u16 hb = f2bf(hnew);
      yencT[((size_t)(t*4 + bg)*1024 + zg*32 + ghc)*16 + gb] = hb;
      if (t == TXX-1){
        int bglob = bg*16 + gb;
        int col = zg*32 + ghc;
        hdec[(size_t)bglob*HH + col] = hb;
        cdec[(size_t)col*BB + bglob] = cnew;
        AdecA[(size_t)bglob*2080 + 1025 + col] = hb;
      }
    }
  }
}

// ---------------- Eenc = y_enc @ w1b[:H] + b1 (bf16 out, MFMA) ---------------
__global__ __launch_bounds__(256) void eenc_mfma(
    const u16* __restrict__ yencT, const u16* __restrict__ w1b,
    const float* __restrict__ b1, u16* __restrict__ eenc)
{
  __shared__ u16 As[4096];
  __shared__ u16 Bs[64*40];
  const int tid = threadIdx.x;
  const int l = tid&63, wm = tid>>6;
  const int c = l&15, koct = l>>4;
  const int t0 = blockIdx.x*2, n0 = blockIdx.y*64;
  const unsigned ab = (unsigned)(size_t)(void*)As;
  f32x4 acc[2][4];
  #pragma unroll
  for (int a=0;a<2;++a)
    #pragma unroll
    for (int b=0;b<4;++b) acc[a][b] = (f32x4){0.f,0.f,0.f,0.f};

  for (int k0=0; k0<HH; k0+=32){
    #pragma unroll
    for (int p=0; p<2; ++p){
      int e = p*256 + tid;
      int sub = e>>6, w16 = e&63;
      const u16* gsrc = yencT + ((size_t)((t0 + (sub>>2))*4 + (sub&3))*1024 + k0)*16 + w16*8;
      *(short8*)((char*)As + e*16) = *(const short8*)gsrc;
    }
    #pragma unroll
    for (int p=0; p<8; ++p){
      int e = p*256 + tid;
      int kk = e>>6, col = e&63;
      int k2 = kk & 15;
      int slot = (k2>>2)*8 + ((kk&16)?4:0) + (k2&3);
      Bs[col*40 + slot] = w1b[(size_t)(k0+kk)*UU + n0 + col];
    }
    __syncthreads();
    unsigned long long r00 = tr16(ab + wm*1024 + l*8);
    unsigned long long r01 = tr16(ab + wm*1024 + 512 + l*8);
    unsigned long long r10 = tr16(ab + (wm+4)*1024 + l*8);
    unsigned long long r11 = tr16(ab + (wm+4)*1024 + 512 + l*8);
    asm volatile("s_waitcnt lgkmcnt(0)" ::: "memory");
    __builtin_amdgcn_sched_barrier(0);
    union { unsigned long long q[2]; short8 s; } u0, u1;
    u0.q[0]=r00; u0.q[1]=r01;
    u1.q[0]=r10; u1.q[1]=r11;
    #pragma unroll
    for (int nt=0; nt<4; ++nt){
      short8 bf = *(const short8*)((const char*)Bs + (nt*16+c)*80 + koct*16);
      acc[0][nt] = __builtin_amdgcn_mfma_f32_16x16x32_bf16(u0.s, bf, acc[0][nt], 0,0,0);
      acc[1][nt] = __builtin_amdgcn_mfma_f32_16x16x32_bf16(u1.s, bf, acc[1][nt], 0,0,0);
    }
    __syncthreads();
  }
  float sbn[4];
  #pragma unroll
  for (int nt=0; nt<4; ++nt) sbn[nt] = b1[n0 + nt*16 + c];
  #pragma unroll
  for (int s=0; s<2; ++s){
    int sub = wm + s*4;
    int t = t0 + (sub>>2), g = sub&3;
    #pragma unroll
    for (int nt=0; nt<4; ++nt){
      #pragma unroll
      for (int j=0; j<4; ++j){
        int b = g*16 + koct*4 + j;
        eenc[((size_t)b*TXX + t)*UU + n0 + nt*16 + c] = f2bf(acc[s][nt][j] + sbn[nt]);
      }
    }
  }
}

// ---------------- hW = h @ w1b[H:] (fallback, LDS gather) --------------------
__global__ __launch_bounds__(256) void hw_mfma(
    const u16* __restrict__ hdec, const u16* __restrict__ w1b,
    float* __restrict__ hW)
{
  extern __shared__ char smem[];
  u16* As = (u16*)smem;
  u16* Ws = (u16*)(smem + 66560);
  const int tid = threadIdx.x;
  const int l = tid&63, w = tid>>6;
  const int c = l&15, koct = l>>4;
  const int u0 = blockIdx.x*16;
  f32x4 acc = {0.f,0.f,0.f,0.f};
  for (int ch=0; ch<2; ++ch){
    #pragma unroll
    for (int p=0; p<16; ++p){
      int e = p*256 + tid;
      int row = e>>6, k16 = e&63;
      *(short8*)((char*)As + row*1040 + k16*16) =
        *(const short8*)(hdec + (size_t)row*HH + ch*512 + k16*8);
    }
    #pragma unroll
    for (int p=0; p<32; ++p){
      int e = p*256 + tid;
      int kk = e>>4, cc = e&15;
      Ws[kk*19 + cc] = w1b[(size_t)(HH + ch*512 + kk)*UU + u0 + cc];
    }
    __syncthreads();
    #pragma unroll
    for (int s=0; s<16; ++s){
      short8 af = *(const short8*)((const char*)As + (w*16+c)*1040 + s*64 + koct*16);
      short8 bf;
      #pragma unroll
      for (int i=0; i<8; ++i) bf[i] = (short)Ws[(s*32 + koct*8 + i)*19 + c];
      acc = __builtin_amdgcn_mfma_f32_16x16x32_bf16(af, bf, acc, 0,0,0);
    }
    __syncthreads();
  }
  #pragma unroll
  for (int j=0; j<4; ++j)
    hW[(size_t)(w*16 + koct*4 + j)*UU + u0 + c] = acc[j];
}

// ---------------- hW (packed-weight variant) ---------------------------------
__global__ __launch_bounds__(256) void hw_mfma_p(
    const u16* __restrict__ hdec, const u16* __restrict__ whpack,
    float* __restrict__ hW)
{
  extern __shared__ char smem[];
  u16* As = (u16*)smem;              // 64 x 1040 B = 66560
  const int tid = threadIdx.x;
  const int l = tid&63, w = tid>>6;
  const int c = l&15, koct = l>>4;
  const int bid = blockIdx.x;
  f32x4 acc = {0.f,0.f,0.f,0.f};
  for (int ch=0; ch<2; ++ch){
    #pragma unroll
    for (int p=0; p<16; ++p){
      int e = p*256 + tid;
      int row = e>>6, k16 = e&63;
      *(short8*)((char*)As + row*1040 + k16*16) =
        *(const short8*)(hdec + (size_t)row*HH + ch*512 + k16*8);
    }
    __syncthreads();
    const u16* wp = whpack + (((size_t)bid*2 + ch)*16)*512;
    #pragma unroll
    for (int s=0; s<16; ++s){
      short8 af = *(const short8*)((const char*)As + (w*16+c)*1040 + s*64 + koct*16);
      short8 bf = *(const short8*)(wp + s*512 + l*8);
      acc = __builtin_amdgcn_mfma_f32_16x16x32_bf16(af, bf, acc, 0,0,0);
    }
    __syncthreads();
  }
  #pragma unroll
  for (int j=0; j<4; ++j)
    hW[(size_t)(w*16 + koct*4 + j)*UU + blockIdx.x*16 + c] = acc[j];
}

// ---------------- fused scores + softmax (per-b block) -----------------------
__global__ __launch_bounds__(512) void att_fused(
  const u16* __restrict__ eenc, const float* __restrict__ hW,
  const float* __restrict__ w2, const float* __restrict__ b2v,
  float* __restrict__ wat, float* __restrict__ outw, int writeOut)
{
  __shared__ float sc[512];
  __shared__ float red[512];
  const int tid = threadIdx.x;
  const int l = tid & 63, w = tid >> 6;
  const int b = blockIdx.x;
  const int u0 = l*8;
  float4 hw0 = *(const float4*)(hW + (size_t)b*UU + u0);
  float4 hw1 = *(const float4*)(hW + (size_t)b*UU + u0 + 4);
  float4 w20 = *(const float4*)(w2 + u0);
  float4 w21 = *(const float4*)(w2 + u0 + 4);
  const float bb = b2v[0];
  for (int i=0; i<64; ++i){
    int t = w*64 + i;
    uint4 ev = *(const uint4*)(eenc + ((size_t)b*TXX + t)*UU + u0);
    float sum;
    sum  = tanhfast(bf2f((u16)(ev.x & 0xffff)) + hw0.x) * w20.x;
    sum += tanhfast(bf2f((u16)(ev.x >> 16   )) + hw0.y) * w20.y;
    sum += tanhfast(bf2f((u16)(ev.y & 0xffff)) + hw0.z) * w20.z;
    sum += tanhfast(bf2f((u16)(ev.y >> 16   )) + hw0.w) * w20.w;
    sum += tanhfast(bf2f((u16)(ev.z & 0xffff)) + hw1.x) * w21.x;
    sum += tanhfast(bf2f((u16)(ev.z >> 16   )) + hw1.y) * w21.y;
    sum += tanhfast(bf2f((u16)(ev.w & 0xffff)) + hw1.z) * w21.z;
    sum += tanhfast(bf2f((u16)(ev.w >> 16   )) + hw1.w) * w21.w;
    #pragma unroll
    for (int off=32; off; off>>=1) sum += __shfl_down(sum, off);
    if (l == 0) sc[t] = fmaxf(sum + bb, 0.f);
  }
  __syncthreads();
  float v = sc[tid];
  red[tid] = v;
  __syncthreads();
  for (int s=256; s; s>>=1){ if (tid<s) red[tid] = fmaxf(red[tid], red[tid+s]); __syncthreads(); }
  float m = red[0];
  __syncthreads();
  float ex = __expf(v - m);
  red[tid] = ex;
  __syncthreads();
  for (int s=256; s; s>>=1){ if (tid<s) red[tid] += red[tid+s]; __syncthreads(); }
  float wv = ex / red[0];
  wat[(size_t)b*TXX + tid] = wv;
  if (writeOut) outw[64 + (size_t)b*TXX + tid] = wv;
}

// ---------------- ctx fallback (r4 ctx_sum) ----------------------------------
__global__ __launch_bounds__(512) void ctx_sum(
  const float* __restrict__ e2, const u16* __restrict__ yencT,
  u16* __restrict__ Adec)
{
  extern __shared__ float wl[];
  const int tid = threadIdx.x;
  const int h0 = blockIdx.x*16;
  {
    int b = tid>>3, t0 = (tid&7)*64;
    for (int i=0; i<64; i+=4){
      float4 v = *(const float4*)(e2 + b*TXX + t0 + i);
      wl[(t0+i+0)*65 + b] = v.x; wl[(t0+i+1)*65 + b] = v.y;
      wl[(t0+i+2)*65 + b] = v.z; wl[(t0+i+3)*65 + b] = v.w;
    }
  }
  __syncthreads();
  const int b2 = tid&15, hh = (tid>>4)&15, gg = tid>>8;
  const int g0 = gg*2, g1 = g0+1;
  const int h = h0 + hh;
  float acc0=0.f, acc1=0.f;
  for (int t=0; t<TXX; ++t){
    float w0 = wl[t*65 + g0*16 + b2];
    float w1 = wl[t*65 + g1*16 + b2];
    u16 y0 = yencT[((size_t)(t*4+g0)*1024 + h)*16 + b2];
    u16 y1 = yencT[((size_t)(t*4+g1)*1024 + h)*16 + b2];
    acc0 = fmaf(w0, bf2f(y0), acc0);
    acc1 = fmaf(w1, bf2f(y1), acc1);
  }
  Adec[(size_t)(g0*16+b2)*2080 + 1 + h] = f2bf(acc0);
  Adec[(size_t)(g1*16+b2)*2080 + 1 + h] = f2bf(acc1);
}

// ---------------- ctx two-stage: part over t-chunks --------------------------
// grid (64 h-slices of 16, 4 t-chunks of 128), 512 thr
__global__ __launch_bounds__(512) void ctx_part(
  const float* __restrict__ wat, const u16* __restrict__ yencT,
  float* __restrict__ part)
{
  extern __shared__ float wl[];      // [64 b][129] f32 chunk = 33024 B
  const int tid = threadIdx.x;
  const int h0 = blockIdx.x*16, tc = blockIdx.y;
  #pragma unroll
  for (int p=0; p<16; ++p){
    int e = p*512 + tid;
    int b = e>>7, tt = e&127;
    wl[b*129 + tt] = wat[(size_t)b*TXX + tc*128 + tt];
  }
  __syncthreads();
  const int b2 = tid&15, hh = (tid>>4)&15, gg = tid>>8;
  const int g0 = gg*2, g1 = g0+1;
  const int h = h0 + hh;
  float acc0=0.f, acc1=0.f;
  #pragma unroll 4
  for (int tt=0; tt<128; ++tt){
    int t = tc*128 + tt;
    float w0 = wl[(g0*16+b2)*129 + tt];
    float w1 = wl[(g1*16+b2)*129 + tt];
    u16 y0 = yencT[((size_t)(t*4+g0)*1024 + h)*16 + b2];
    u16 y1 = yencT[((size_t)(t*4+g1)*1024 + h)*16 + b2];
    acc0 = fmaf(w0, bf2f(y0), acc0);
    acc1 = fmaf(w1, bf2f(y1), acc1);
  }
  part[((size_t)tc*64 + g0*16 + b2)*1024 + h] = acc0;
  part[((size_t)tc*64 + g1*16 + b2)*1024 + h] = acc1;
}

__global__ __launch_bounds__(256) void ctx_red(
  const float* __restrict__ part, u16* __restrict__ Adec)
{
  int idx = blockIdx.x*256 + threadIdx.x;   // 65536 = 64 b x 1024 h
  int b = idx >> 10, h = idx & 1023;
  float s = part[(size_t)b*1024 + h] + part[(size_t)(64+b)*1024 + h]
          + part[(size_t)(128+b)*1024 + h] + part[(size_t)(192+b)*1024 + h];
  Adec[(size_t)b*2080 + 1 + h] = f2bf(s);
}

// ---------------- decoder LSTM fallback (r4) ---------------------------------
__global__ __launch_bounds__(256) void dec_mfma(
    const u16* __restrict__ Adec, const float* __restrict__ dec_k_,
    const float* __restrict__ dec_rk_, const float* __restrict__ dec_b_,
    float* __restrict__ cdec, u16* __restrict__ hdec, u16* __restrict__ Anxt)
{
  extern __shared__ char smem[];
  u16* As = (u16*)smem;
  u16* Ws = (u16*)(smem + 54272);
  float* zex = (float*)(smem + 54272 + 15808);
  const int tid = threadIdx.x;
  const int l = tid&63, w = tid>>6;
  const int c = l&15, koct = l>>4;
  const int j0 = blockIdx.x*4;
  const int gcol = (c>>2)*1024 + j0 + (c&3);
  f32x4 acc = {0.f,0.f,0.f,0.f};
  for (int ch=0; ch<5; ++ch){
    for (int p=0; p<13; ++p){
      int e = p*256 + tid;
      int row = e/52, k16 = e - row*52;
      *(short8*)((char*)As + row*848 + k16*16) =
        *(const short8*)(Adec + (size_t)row*2080 + ch*416 + k16*8);
    }
    for (int p=0; p<26; ++p){
      int e = p*256 + tid;
      int kl = e>>4, cc = e&15;
      int kg = ch*416 + kl;
      int col = (cc>>2)*1024 + j0 + (cc&3);
      float v;
      if (kg <= 1024) v = dec_k_[(size_t)kg*G4 + col];
      else if (kg <= 2048) v = dec_rk_[(size_t)(kg-1025)*G4 + col];
      else v = 0.f;
      Ws[kl*19 + cc] = f2bf(v);
    }
    __syncthreads();
    #pragma unroll
    for (int s=0; s<13; ++s){
      short8 af = *(const short8*)((const char*)As + (w*16+c)*848 + s*64 + koct*16);
      short8 bf;
      #pragma unroll
      for (int i=0; i<8; ++i) bf[i] = (short)Ws[(s*32 + koct*8 + i)*19 + c];
      acc = __builtin_amdgcn_mfma_f32_16x16x32_bf16(af, bf, acc, 0,0,0);
    }
    __syncthreads();
  }
  const float sbias = dec_b_[gcol];
  #pragma unroll
  for (int j=0; j<4; ++j)
    zex[(w*16 + koct*4 + j)*17 + c] = acc[j] + sbias;
  __syncthreads();
  {
    int b = tid&63, jj = tid>>6;
    float zi = zex[b*17 + jj], zf = zex[b*17+4+jj], zg = zex[b*17+8+jj], zo = zex[b*17+12+jj];
    float cold = cdec[(j0+jj)*BB + b];
    float cnew = sigm(zf)*cold + sigm(zi)*tanhfast(zg);
    float hnew = sigm(zo)*tanhfast(cnew);
    cdec[(j0+jj)*BB + b] = cnew;
    u16 hb = f2bf(hnew);
    hdec[b*HH + j0 + jj] = hb;
    Anxt[(size_t)b*2080 + 1025 + j0 + jj] = hb;
  }
}

// ---------------- decoder LSTM packed-weight variant -------------------------
__global__ __launch_bounds__(256) void dec_mfma_p(
    const u16* __restrict__ Adec, const u16* __restrict__ wpack,
    const float* __restrict__ dec_b_,
    float* __restrict__ cdec, u16* __restrict__ hdec, u16* __restrict__ Anxt)
{
  extern __shared__ char smem[];
  u16* As = (u16*)smem;                    // 64 x 848 B = 54272
  float* zex = (float*)(smem + 54272);     // 4352
  const int tid = threadIdx.x;
  const int l = tid&63, w = tid>>6;
  const int c = l&15, koct = l>>4;
  const int bid = blockIdx.x;
  const int j0 = bid*4;
  const int gcol = (c>>2)*1024 + j0 + (c&3);
  f32x4 acc = {0.f,0.f,0.f,0.f};
  for (int ch=0; ch<5; ++ch){
    for (int p=0; p<13; ++p){
      int e = p*256 + tid;
      int row = e/52, k16 = e - row*52;
      *(short8*)((char*)As + row*848 + k16*16) =
        *(const short8*)(Adec + (size_t)row*2080 + ch*416 + k16*8);
    }
    __syncthreads();
    const u16* wp = wpack + (((size_t)bid*5 + ch)*13)*512;
    #pragma unroll
    for (int s=0; s<13; ++s){
      short8 af = *(const short8*)((const char*)As + (w*16+c)*848 + s*64 + koct*16);
      short8 bf = *(const short8*)(wp + s*512 + l*8);
      acc = __builtin_amdgcn_mfma_f32_16x16x32_bf16(af, bf, acc, 0,0,0);
    }
    __syncthreads();
  }
  const float sbias = dec_b_[gcol];
  #pragma unroll
  for (int j=0; j<4; ++j)
    zex[(w*16 + koct*4 + j)*17 + c] = acc[j] + sbias;
  __syncthreads();
  {
    int b = tid&63, jj = tid>>6;
    float zi = zex[b*17 + jj], zf = zex[b*17+4+jj], zg = zex[b*17+8+jj], zo = zex[b*17+12+jj];
    float cold = cdec[(j0+jj)*BB + b];
    float cnew = sigm(zf)*cold + sigm(zi)*tanhfast(zg);
    float hnew = sigm(zo)*tanhfast(cnew);
    cdec[(j0+jj)*BB + b] = cnew;
    u16 hb = f2bf(hnew);
    hdec[b*HH + j0 + jj] = hb;
    Anxt[(size_t)b*2080 + 1025 + j0 + jj] = hb;
  }
}

// ---------------- weight pre-pack kernels ------------------------------------
__global__ __launch_bounds__(256) void conv_dec(
  const float* __restrict__ dec_k_, const float* __restrict__ dec_rk_,
  u16* __restrict__ wpack)
{
  const int jb = blockIdx.x;
  for (int e = threadIdx.x; e < 33280; e += 256){
    int i = e & 7, l = (e>>3) & 63;
    int grp = e >> 9;              // 0..64
    int s = grp % 13, ch = grp / 13;
    int c = l & 15, koct = l >> 4;
    int kg = ch*416 + s*32 + koct*8 + i;
    int col = (c>>2)*1024 + jb*4 + (c&3);
    float v;
    if (kg <= 1024) v = dec_k_[(size_t)kg*G4 + col];
    else if (kg <= 2048) v = dec_rk_[(size_t)(kg-1025)*G4 + col];
    else v = 0.f;
    wpack[((((size_t)jb*5 + ch)*13 + s)*64 + l)*8 + i] = f2bf(v);
  }
}

__global__ __launch_bounds__(256) void conv_wh(
  const float* __restrict__ w1, u16* __restrict__ whpack)
{
  const int ub = blockIdx.x;
  for (int e = threadIdx.x; e < 16384; e += 256){
    int i = e & 7, l = (e>>3) & 63;
    int grp = e >> 9;              // 0..31
    int s = grp & 15, ch = grp >> 4;
    int c = l & 15, koct = l >> 4;
    int kg = HH + ch*512 + s*32 + koct*8 + i;
    float v = w1[(size_t)kg*UU + ub*16 + c];
    whpack[((((size_t)ub*2 + ch)*16 + s)*64 + l)*8 + i] = f2bf(v);
  }
}

// ---------------- final y = h @ fin_w + fin_b --------------------------------
__global__ __launch_bounds__(256) void final_y(
  const u16* __restrict__ hdec, const float* __restrict__ fw,
  const float* __restrict__ fb, float* __restrict__ yprev,
  u16* __restrict__ Anxt, float* __restrict__ outy, int writeOut)
{
  __shared__ float red[256];
  const int b = blockIdx.x, tid = threadIdx.x;
  ushort4 hv = *(const ushort4*)(hdec + (size_t)b*HH + tid*4);
  float4 wv = *(const float4*)(fw + tid*4);
  red[tid] = bf2f(hv.x)*wv.x + bf2f(hv.y)*wv.y + bf2f(hv.z)*wv.z + bf2f(hv.w)*wv.w;
  __syncthreads();
  for (int sft=128; sft; sft>>=1){ if (tid<sft) red[tid] += red[tid+sft]; __syncthreads(); }
  if (tid==0){
    float y = red[0] + fb[0];
    yprev[b] = y;
    Anxt[(size_t)b*2080] = f2bf(y);
    if (writeOut) outy[b] = y;
  }
}

__global__ void init_yprev(const float* __restrict__ x, float* __restrict__ yprev,
                           u16* __restrict__ AdecA){
  int b = threadIdx.x;
  if (b < BB){
    float v = x[(size_t)b*TXX*DD + (size_t)(TXX-1)*DD + (DD-1)];
    yprev[b] = v;
    AdecA[(size_t)b*2080] = f2bf(v);
  }
}

__global__ __launch_bounds__(256) void conv_w1(const float* __restrict__ w1, u16* __restrict__ w1b){
  int e = blockIdx.x*256 + threadIdx.x;
  w1b[e] = f2bf(w1[e]);
}

extern "C" void kernel_launch(void* const* d_in, const int* in_sizes, int n_in,
                              void* d_out, int out_size, void* d_ws, size_t ws_size,
                              hipStream_t stream)
{
  (void)in_sizes; (void)n_in; (void)out_size;
  const float* x      = (const float*)d_in[0];
  const float* enc_k  = (const float*)d_in[1];
  const float* enc_rk = (const float*)d_in[2];
  const float* enc_b  = (const float*)d_in[3];
  const float* dec_k  = (const float*)d_in[4];
  const float* dec_rk = (const float*)d_in[5];
  const float* dec_b  = (const float*)d_in[6];
  const float* att_w1 = (const float*)d_in[7];
  const float* att_b1 = (const float*)d_in[8];
  const float* att_w2 = (const float*)d_in[9];
  const float* att_b2 = (const float*)d_in[10];
  const float* fin_w  = (const float*)d_in[11];
  const float* fin_b  = (const float*)d_in[12];
  float* out = (float*)d_out;

  char* wsp = (char*)d_ws;
  u16*   yencT = (u16*)(wsp);                     // 67108864
  u16*   eenc  = (u16*)(wsp + 67108864);          // 33554432
  u16*   w1b   = (u16*)(wsp + 100663296);         // 2097152
  u16*   hdec  = (u16*)(wsp + 102760448);         // 131072
  u16*   AdecA = (u16*)(wsp + 102891520);         // 266240
  u16*   AdecB = (u16*)(wsp + 103157760);         // 266240
  float* cdec  = (float*)(wsp + 103424000);       // 262144
  float* hW    = (float*)(wsp + 103686144);       // 131072
  float* e2    = (float*)(wsp + 103817216);       // 131072 (wat)
  float* yprev = (float*)(wsp + 103948288);       // 256
  unsigned* bar= (unsigned*)(wsp + 103948544);    // 4096
  float* part  = (float*)(wsp + 103952640);       // 1048576
  u16*   whpack= (u16*)(wsp + 105001216);         // 1048576
  u16*   wpack = (u16*)(wsp + 106049792);         // 17039360 -> 123089152
  const bool plus = (ws_size >= (size_t)123089152);

  hipFuncSetAttribute((const void*)enc_persist, hipFuncAttributeMaxDynamicSharedMemorySize, 100352);
  hipFuncSetAttribute((const void*)hw_mfma,     hipFuncAttributeMaxDynamicSharedMemorySize, 86016);
  hipFuncSetAttribute((const void*)hw_mfma_p,   hipFuncAttributeMaxDynamicSharedMemorySize, 66560);
  hipFuncSetAttribute((const void*)dec_mfma,    hipFuncAttributeMaxDynamicSharedMemorySize, 74432);
  hipFuncSetAttribute((const void*)dec_mfma_p,  hipFuncAttributeMaxDynamicSharedMemorySize, 58624);
  hipFuncSetAttribute((const void*)ctx_sum,     hipFuncAttributeMaxDynamicSharedMemorySize, 133120);
  hipFuncSetAttribute((const void*)ctx_part,    hipFuncAttributeMaxDynamicSharedMemorySize, 33024);

  hipMemsetAsync(bar, 0, 4096, stream);
  init_yprev<<<1, 64, 0, stream>>>(x, yprev, AdecA);
  conv_w1<<<4096, 256, 0, stream>>>(att_w1, w1b);
  if (plus){
    conv_dec<<<256, 256, 0, stream>>>(dec_k, dec_rk, wpack);
    conv_wh<<<32, 256, 0, stream>>>(att_w1, whpack);
  }

  enc_persist<<<128, 512, 100352, stream>>>(x, enc_k, enc_rk, enc_b, yencT, hdec, cdec, AdecA, bar);

  eenc_mfma<<<dim3(256,8), 256, 0, stream>>>(yencT, w1b, att_b1, eenc);

  for (int s=0; s<TYY; ++s){
    int last = (s == TYY-1);
    u16* Acur = (s&1)? AdecB : AdecA;
    u16* Anxt = (s&1)? AdecA : AdecB;
    if (plus) hw_mfma_p<<<32, 256, 66560, stream>>>(hdec, whpack, hW);
    else      hw_mfma  <<<32, 256, 86016, stream>>>(hdec, w1b, hW);
    att_fused<<<64, 512, 0, stream>>>(eenc, hW, att_w2, att_b2, e2, out, last);
    if (plus){
      ctx_part<<<dim3(64,4), 512, 33024, stream>>>(e2, yencT, part);
      ctx_red <<<256, 256, 0, stream>>>(part, Acur);
    } else {
      ctx_sum <<<64, 512, 133120, stream>>>(e2, yencT, Acur);
    }
    if (plus) dec_mfma_p<<<256, 256, 58624, stream>>>(Acur, wpack, dec_b, cdec, hdec, Anxt);
    else      dec_mfma  <<<256, 256, 74432, stream>>>(Acur, dec_k, dec_rk, dec_b, cdec, hdec, Anxt);
    final_y  <<<64, 256, 0, stream>>>(hdec, fin_w, fin_b, yprev, Anxt, out, last);
  }
}